// Round 1
// baseline (162.312 us; speedup 1.0000x reference)
//
#include <hip/hip_runtime.h>
#include <math.h>

#define L_LEN 16384
#define M_LEN 8192
#define KT_LEN 4096
#define BB 32
#define NTPL 50
#define SPEC_STRIDE 8224   // complex slots per signal (>= 8193)
#define NSIG 166           // 64 x-signals + 2 w-signals + 100 templates
#define NT 1024
#define PI_F 3.14159265358979323846f
// cos/sin(2*pi/16): stage-4 twiddle base (radix-8 ladder)
#define C8 0.92387953251128674f
#define S8 0.38268343236508978f

typedef float cf2 __attribute__((ext_vector_type(2)));

// Lessons encoded in this structure:
//  R5: scattered per-lane twiddle table loads stall VMEM -> power chain from 1 load.
//  R6: XOR swizzle + cf2 packed math + algebraic per-stage indices = best layout.
//  R7: +1-per-32 pad layout TRIPLES bank conflicts vs XOR swizzle. Don't.
//  R8: __shfl_xor compiles to ds_bpermute (LDS pipe!) - shfl-based stage fusion
//      is slower than plain LDS stages + b128 final pass. Don't.
//  R9 (this round): radix-16/512-thr capped occupancy at 16 waves/CU (LDS 64KB
//      -> 2 blocks/CU, 8 waves each) with VALUBusy 73%. Radix 8,8,8,8,2 gives
//      1024 butterflies/stage -> 1024-thr blocks -> 32 waves/CU at same LDS.
//      Same XOR swizzle verified <=2-way (free) for strides 1024/128/16/2.

__device__ __forceinline__ cf2 cmul(cf2 a, cf2 b) {
    cf2 byx = __builtin_shufflevector(b, b, 1, 0);   // (by,bx)
    return (cf2){a.x, a.x} * b + (cf2){-a.y, a.y} * byx;
}
__device__ __forceinline__ cf2 cmulc(cf2 a, cf2 b) { // a * conj(b)
    return a * (cf2){b.x, b.x} + (cf2){a.y, -a.x} * (cf2){b.y, b.y};
}
template<int SIGN>
__device__ __forceinline__ cf2 rot90(cf2 z) {
    return (SIGN < 0) ? (cf2){z.y, -z.x} : (cf2){-z.y, z.x};
}
template<int SIGN>
__device__ __forceinline__ cf2 ldT(const cf2* __restrict__ T, int idx) {
    cf2 t = T[idx];
    if (SIGN > 0) t.y = -t.y;
    return t;
}

// LDS bank swizzle. Even XOR keeps float4 pair adjacency; involution.
__device__ __forceinline__ int swz(int i) { return i ^ (((i >> 5) & 15) << 1); }

// Position of frequency f after radix 8,8,8,8,2 DIF stages (digit reversal).
__device__ __forceinline__ int pos8(int f) {
    return ((f & 7) << 10) | (((f >> 3) & 7) << 7) |
           (((f >> 6) & 7) << 4) | (((f >> 9) & 7) << 1) | ((f >> 12) & 1);
}

// 8-point DFT in registers, natural order (DIF split 2x4).
template<int SIGN>
__device__ __forceinline__ void dft8(cf2 x[8]) {
    const float R2 = 0.70710678118654752f;
    const cf2 w81 = { R2, SIGN * R2 };     // W8^1 (fwd: e^{-i pi/4})
    const cf2 w83 = { -R2, SIGN * R2 };    // W8^3
    cf2 u0 = x[0] + x[4], u1 = x[1] + x[5], u2 = x[2] + x[6], u3 = x[3] + x[7];
    cf2 v0 = x[0] - x[4];
    cf2 v1 = cmul(x[1] - x[5], w81);
    cf2 v2 = rot90<SIGN>(x[2] - x[6]);
    cf2 v3 = cmul(x[3] - x[7], w83);
    // DFT4(u) -> X[0,2,4,6]
    cf2 t0 = u0 + u2, t2 = u0 - u2;
    cf2 t1 = u1 + u3, t3 = rot90<SIGN>(u1 - u3);
    x[0] = t0 + t1; x[2] = t2 + t3; x[4] = t0 - t1; x[6] = t2 - t3;
    // DFT4(v) -> X[1,3,5,7]
    cf2 s0 = v0 + v2, s2 = v0 - v2;
    cf2 s1 = v1 + v3, s3 = rot90<SIGN>(v1 - v3);
    x[1] = s0 + s1; x[3] = s2 + s3; x[5] = s0 - s1; x[7] = s2 - s3;
}

// Radix-8 butterfly at 8 precomputed LDS indices; outer twiddles from a
// single w1 via power chain.
template<int SIGN>
__device__ __forceinline__ void butterfly8(cf2* A, const int idx[8], cf2 w1) {
    cf2 x[8];
    #pragma unroll
    for (int n = 0; n < 8; ++n) x[n] = A[idx[n]];
    dft8<SIGN>(x);
    A[idx[0]] = x[0];
    A[idx[1]] = cmul(x[1], w1);
    const cf2 w2 = cmul(w1, w1);
    A[idx[2]] = cmul(x[2], w2);
    const cf2 w3 = cmul(w1, w2);
    A[idx[3]] = cmul(x[3], w3);
    const cf2 w4 = cmul(w2, w2);
    A[idx[4]] = cmul(x[4], w4);
    A[idx[5]] = cmul(x[5], cmul(w1, w4));
    A[idx[6]] = cmul(x[6], cmul(w2, w4));
    A[idx[7]] = cmul(x[7], cmul(w3, w4));
}

// Per-stage swizzled index sets, algebraically reduced (bits of i never carry
// across the XOR fields; all verified <=2-way bank aliasing per wave):
// stage1: swz(t+1024n)                 = swz(t) + 1024n
// stage2: swz(b*1024+j+128n)           = b*1024 + 128n + (jsw ^ ((n&3)<<3)),
//         jsw = j ^ (((j>>5)&3)<<1)                           (j in [0,128))
// stage3: swz(b*128+j+16n)             = (b*128+j+16n) ^ ((b&3)<<3) ^ ((n>>1)<<1)
// stage4: swz(b*16+j+2n)               = base ^ ((2n)^xv), X=((b>>1)&15)<<1,
//         base = ((b<<4)|j) ^ (X&16), xv = X&14

// ---------------------------------------------------------------------------
// Kernel 1: forward real FFT (length 16384) via 8192-pt complex FFT.
// Blocks [NSIG, NSIG+16) build the twiddle table T (used by inv only) with a
// quadrant-reduced float sincos (no fp64 -> no VGPR inflation at LB(1024,8)).
// W blocks (sig 64/65) write V(f) = conj(W(f)) * e^{-i pi k/8192},
// k = 4094*f mod 16384 — absorbs the old premul kernel entirely.
// ---------------------------------------------------------------------------
__global__ __launch_bounds__(NT, 8)
void fwd_fft_kernel(const float* __restrict__ xi, const float* __restrict__ w,
                    const float* __restrict__ tmpl, cf2* __restrict__ Tw,
                    cf2* __restrict__ spec) {
    __shared__ __attribute__((aligned(16))) cf2 A[M_LEN];   // 64 KB
    const int sig = blockIdx.x;
    const int tid = threadIdx.x;

    if (sig >= NSIG) {   // twiddle writer: T[k] = e^{-2 pi i k / 16384}
        const int k = (sig - NSIG) * NT + tid;
        const int quad = k >> 12, mm = k & 4095;
        float s, c; __sincosf(PI_F * (float)mm / 8192.f, &s, &c);
        cf2 v;   // (cos th, -sin th), th = pi k/8192 = quad*pi/2 + t
        if      (quad == 0) v = (cf2){ c, -s};
        else if (quad == 1) v = (cf2){-s, -c};
        else if (quad == 2) v = (cf2){-c,  s};
        else                v = (cf2){ s,  c};
        Tw[k] = v;
        return;
    }

    const float* src;
    int nre;
    if (sig < 64)      { src = xi   + sig * L_LEN;         nre = L_LEN; }
    else if (sig < 66) { src = w    + (sig - 64) * L_LEN;  nre = L_LEN; }
    else               { src = tmpl + (sig - 66) * KT_LEN; nre = KT_LEN; }
    const bool isW = (sig >= 64 && sig < 66);
    const int nc = nre >> 1;
    const float4* s4 = (const float4*)src;
    const int g0 = tid ^ ((tid >> 4) & 15);   // swz(2g)/2 for g = tid+1024m
    #pragma unroll
    for (int m = 0; m < 4; ++m) {
        const int u = 2*tid + 2048*m;
        float4 vv = (u < nc) ? s4[tid + 1024*m] : make_float4(0.f, 0.f, 0.f, 0.f);
        ((float4*)A)[g0 + 1024*m] = vv;
    }
    __syncthreads();

    {   // stage 1: stride 1024, w1 = W_8192^tid
        int idx[8]; const int b0 = swz(tid);
        #pragma unroll
        for (int n = 0; n < 8; ++n) idx[n] = b0 + 1024*n;
        float sn, cs; __sincosf(-PI_F * (float)(2*tid) / 8192.f, &sn, &cs);
        butterfly8<-1>(A, idx, (cf2){cs, sn});
    }
    __syncthreads();
    {   // stage 2: stride 128, w1 = W_1024^j
        const int blk = tid >> 7, j = tid & 127, jb = blk*1024;
        const int jsw = j ^ (((j >> 5) & 3) << 1);
        int idx[8];
        #pragma unroll
        for (int n = 0; n < 8; ++n) idx[n] = jb + 128*n + (jsw ^ ((n & 3) << 3));
        float sn, cs; __sincosf(-PI_F * (float)(16*j) / 8192.f, &sn, &cs);
        butterfly8<-1>(A, idx, (cf2){cs, sn});
    }
    __syncthreads();
    {   // stage 3: stride 16, w1 = W_128^j
        const int blk = tid >> 4, j = tid & 15;
        const int base = blk*128 + j, bx = (blk & 3) << 3;
        int idx[8];
        #pragma unroll
        for (int n = 0; n < 8; ++n) idx[n] = (base + 16*n) ^ bx ^ ((n >> 1) << 1);
        float sn, cs; __sincosf(-PI_F * (float)(128*j) / 8192.f, &sn, &cs);
        butterfly8<-1>(A, idx, (cf2){cs, sn});
    }
    __syncthreads();
    {   // stage 4: stride 2, w1 = W_16^j (constant)
        const int blk = tid >> 1, j = tid & 1;
        const int Xa = ((blk >> 1) & 15) << 1;
        const int base = ((blk << 4) | j) ^ (Xa & 16);
        const int xv = Xa & 14;
        int idx[8];
        #pragma unroll
        for (int n = 0; n < 8; ++n) idx[n] = base + ((2*n) ^ xv);
        cf2 w1 = j ? (cf2){C8, -S8} : (cf2){1.f, 0.f};
        butterfly8<-1>(A, idx, w1);
    }
    __syncthreads();
    // Final radix-2 (stride 1, no twiddle), b128 in-place.
    #pragma unroll
    for (int m = 0; m < 4; ++m) {
        float4 pq = ((float4*)A)[g0 + 1024*m];
        ((float4*)A)[g0 + 1024*m] = make_float4(pq.x + pq.z, pq.y + pq.w,
                                                pq.x - pq.z, pq.y - pq.w);
    }
    __syncthreads();

    // Untangle packed result to real-signal spectrum X[f], f = 0..M.
    cf2* out = spec + (size_t)sig * SPEC_STRIDE;
    #pragma unroll
    for (int m = 0; m < 8; ++m) {
        const int f = tid + 1024*m;
        const int fb = (M_LEN - f) & (M_LEN - 1);
        cf2 Za = A[swz(pos8(f))];
        cf2 Zb = A[swz(pos8(fb))];
        cf2 E = (cf2){0.5f*(Za.x + Zb.x), 0.5f*(Za.y - Zb.y)};
        cf2 D = (cf2){Za.x - Zb.x, Za.y + Zb.y};
        cf2 O = (cf2){0.5f*D.y, -0.5f*D.x};
        float sn, cs;
        __sincosf(-PI_F * (float)f / 8192.f, &sn, &cs);
        cf2 val = E + (cf2){cs*O.x - sn*O.y, cs*O.y + sn*O.x};
        if (isW) {   // V(f) = conj(W(f)) * e^{-i pi k/8192}, k exact int mod
            const int k = (4094 * f) & (L_LEN - 1);
            float psn, pcs; __sincosf(-PI_F * (float)k / 8192.f, &psn, &pcs);
            val = cmul((cf2){val.x, -val.y}, (cf2){pcs, psn});
        }
        out[f] = val;
    }
    if (tid == 0) {   // f = 8192
        cf2 Za = A[swz(0)];
        cf2 val = (cf2){Za.x - Za.y, 0.f};
        if (isW) {   // k(8192) = 8192 -> phase = (-1, 0)
            val = (cf2){-val.x, 0.f};
        }
        out[M_LEN] = val;
    }
}

// ---------------------------------------------------------------------------
// Kernel 2: per (b,n,c): S[f] = X[f]*V[f]*conj(H[f]); Hermitian pack fused
// into the product pass; 4 radix-8 LDS stages; final radix-2 fused with max.
// 1024 threads -> 2 blocks/CU -> 32 waves/CU (R9).
// ---------------------------------------------------------------------------
__global__ __launch_bounds__(NT, 8)
void inv_fft_kernel(const cf2* __restrict__ spec, const cf2* __restrict__ T,
                    const float* __restrict__ hh, float* __restrict__ zarr) {
    __shared__ __attribute__((aligned(16))) cf2 A[M_LEN];   // 64 KB
    const int idx0 = blockIdx.x;
    const int c = idx0 & 1;
    const int n = (idx0 >> 1) % NTPL;
    const int b = idx0 / (2 * NTPL);
    const int tid = threadIdx.x;

    const cf2* Xs = spec + (size_t)(b*2 + c)      * SPEC_STRIDE;
    const cf2* Vs = spec + (size_t)(64 + c)       * SPEC_STRIDE;
    const cf2* Hs = spec + (size_t)(66 + n*2 + c) * SPEC_STRIDE;
    const float4* X4 = (const float4*)Xs;
    const float4* V4 = (const float4*)Vs;
    const float4* H4 = (const float4*)Hs;
    const float4* T4 = (const float4*)T;
    const int g0 = tid ^ ((tid >> 4) & 15);

    // Fused product + Hermitian pack: thread t handles f = 2t+2048m+{0,1}
    // (f in [0,4096)) and partners 8192-f. Writes all of Z'[0..8191].
    #pragma unroll
    for (int m = 0; m < 2; ++m) {
        const int u = 2*tid + 2048*m;
        float4 xf = X4[tid + 1024*m], vf = V4[tid + 1024*m], hf = H4[tid + 1024*m];
        cf2 Sa0 = cmulc(cmul((cf2){xf.x, xf.y}, (cf2){vf.x, vf.y}), (cf2){hf.x, hf.y});
        cf2 Sa1 = cmulc(cmul((cf2){xf.z, xf.w}, (cf2){vf.z, vf.w}), (cf2){hf.z, hf.w});
        cf2 Sb0 = cmulc(cmul(Xs[M_LEN - u],     Vs[M_LEN - u]),     Hs[M_LEN - u]);
        cf2 Sb1 = cmulc(cmul(Xs[M_LEN - 1 - u], Vs[M_LEN - 1 - u]), Hs[M_LEN - 1 - u]);
        float4 tw = T4[tid + 1024*m];          // T[u], T[u+1]
        // f = u
        float cs0 = tw.x, sn0 = -tw.y;
        float Ex0 = 0.5f*(Sa0.x + Sb0.x), Ey0 = 0.5f*(Sa0.y - Sb0.y);
        float Dx0 = Sa0.x - Sb0.x,        Dy0 = Sa0.y + Sb0.y;
        float Ox0 = 0.5f*(cs0*Dx0 - sn0*Dy0), Oy0 = 0.5f*(cs0*Dy0 + sn0*Dx0);
        // f = u+1
        float cs1 = tw.z, sn1 = -tw.w;
        float Ex1 = 0.5f*(Sa1.x + Sb1.x), Ey1 = 0.5f*(Sa1.y - Sb1.y);
        float Dx1 = Sa1.x - Sb1.x,        Dy1 = Sa1.y + Sb1.y;
        float Ox1 = 0.5f*(cs1*Dx1 - sn1*Dy1), Oy1 = 0.5f*(cs1*Dy1 + sn1*Dx1);
        ((float4*)A)[g0 + 1024*m] = make_float4(Ex0 - Oy0, Ey0 + Ox0,
                                                Ex1 - Oy1, Ey1 + Ox1);
        if (u > 0) A[swz(M_LEN - u)] = (cf2){Ex0 + Oy0, Ox0 - Ey0};
        A[swz(M_LEN - 1 - u)] = (cf2){Ex1 + Oy1, Ox1 - Ey1};
    }
    if (tid == 0) {   // f = 4096 (self-paired)
        cf2 S = cmulc(cmul(Xs[4096], Vs[4096]), Hs[4096]);
        A[swz(4096)] = (cf2){S.x, -S.y};
    }
    __syncthreads();

    {   // stage 1: stride 1024
        int idx[8]; const int b0 = swz(tid);
        #pragma unroll
        for (int nn = 0; nn < 8; ++nn) idx[nn] = b0 + 1024*nn;
        butterfly8<+1>(A, idx, ldT<+1>(T, 2*tid));
    }
    __syncthreads();
    {   // stage 2: stride 128
        const int blk = tid >> 7, j = tid & 127, jb = blk*1024;
        const int jsw = j ^ (((j >> 5) & 3) << 1);
        int idx[8];
        #pragma unroll
        for (int nn = 0; nn < 8; ++nn) idx[nn] = jb + 128*nn + (jsw ^ ((nn & 3) << 3));
        butterfly8<+1>(A, idx, ldT<+1>(T, 16*j));
    }
    __syncthreads();
    {   // stage 3: stride 16
        const int blk = tid >> 4, j = tid & 15;
        const int base = blk*128 + j, bx = (blk & 3) << 3;
        int idx[8];
        #pragma unroll
        for (int nn = 0; nn < 8; ++nn) idx[nn] = (base + 16*nn) ^ bx ^ ((nn >> 1) << 1);
        butterfly8<+1>(A, idx, ldT<+1>(T, 128*j));
    }
    __syncthreads();
    {   // stage 4: stride 2
        const int blk = tid >> 1, j = tid & 1;
        const int Xa = ((blk >> 1) & 15) << 1;
        const int base = ((blk << 4) | j) ^ (Xa & 16);
        const int xv = Xa & 14;
        int idx[8];
        #pragma unroll
        for (int nn = 0; nn < 8; ++nn) idx[nn] = base + ((2*nn) ^ xv);
        cf2 w1 = j ? (cf2){C8, S8} : (cf2){1.f, 0.f};
        butterfly8<+1>(A, idx, w1);
    }
    __syncthreads();

    // Final radix-2 fused with max over re/im of every time sample (b128).
    float mx = -INFINITY;
    #pragma unroll
    for (int m = 0; m < 4; ++m) {
        float4 pq = ((const float4*)A)[g0 + 1024*m];
        mx = fmaxf(mx, fmaxf(fmaxf(pq.x + pq.z, pq.y + pq.w),
                             fmaxf(pq.x - pq.z, pq.y - pq.w)));
    }
    __syncthreads();   // all reads of A done before reusing it as scratch
    for (int off = 32; off > 0; off >>= 1)
        mx = fmaxf(mx, __shfl_xor(mx, off));
    const int lane = tid & 63, wv = tid >> 6;   // 16 waves
    float* redf = (float*)A;
    if (lane == 0) redf[wv] = mx;
    __syncthreads();
    if (tid == 0) {
        float mm = redf[0];
        for (int i = 1; i < NT/64; ++i) mm = fmaxf(mm, redf[i]);
        zarr[(b*2 + c)*NTPL + n] = mm / ((float)M_LEN * hh[n*2 + c]);
    }
}

// ---------------------------------------------------------------------------
// Kernel 3: tiny CNN/MLP head. One block per batch element.
// ---------------------------------------------------------------------------
__global__ __launch_bounds__(256)
void head_kernel(const float* __restrict__ zarr,
                 const float* __restrict__ W1, const float* __restrict__ b1,
                 const float* __restrict__ W2, const float* __restrict__ b2,
                 const float* __restrict__ W3, const float* __restrict__ b3,
                 const float* __restrict__ W4, const float* __restrict__ b4,
                 float* __restrict__ out) {
    __shared__ float zl[2][NTPL];
    __shared__ float s1[16][48];
    __shared__ float p1[16][16];
    __shared__ float s2[32][14];
    __shared__ float hflat[128];
    __shared__ float h1[32];
    const int b = blockIdx.x, tid = threadIdx.x;

    for (int i = tid; i < 2*NTPL; i += 256) zl[i/NTPL][i%NTPL] = zarr[b*2*NTPL + i];
    __syncthreads();
    for (int i = tid; i < 16*48; i += 256) {
        const int o = i / 48, t = i % 48;
        float acc = b1[o];
        #pragma unroll
        for (int cc = 0; cc < 2; ++cc)
            #pragma unroll
            for (int k = 0; k < 3; ++k)
                acc += zl[cc][t+k] * W1[o*6 + cc*3 + k];
        s1[o][t] = 1.f / (1.f + __expf(-acc));
    }
    __syncthreads();
    for (int i = tid; i < 16*16; i += 256) {
        const int o = i / 16, u = i % 16;
        p1[o][u] = fmaxf(fmaxf(s1[o][3*u], s1[o][3*u+1]), s1[o][3*u+2]);
    }
    __syncthreads();
    for (int i = tid; i < 32*14; i += 256) {
        const int o = i / 14, t = i % 14;
        float acc = b2[o];
        for (int cc = 0; cc < 16; ++cc)
            #pragma unroll
            for (int k = 0; k < 3; ++k)
                acc += p1[cc][t+k] * W2[o*48 + cc*3 + k];
        s2[o][t] = 1.f / (1.f + __expf(-acc));
    }
    __syncthreads();
    for (int i = tid; i < 128; i += 256) {
        const int o = i / 4, u = i % 4;
        hflat[i] = fmaxf(fmaxf(s2[o][3*u], s2[o][3*u+1]), s2[o][3*u+2]);
    }
    __syncthreads();
    if (tid < 32) {
        float acc = b3[tid];
        for (int j = 0; j < 128; ++j) acc += hflat[j] * W3[tid*128 + j];
        h1[tid] = fmaxf(acc, 0.f);
    }
    __syncthreads();
    if (tid < 2) {
        float acc = b4[tid];
        for (int j = 0; j < 32; ++j) acc += h1[j] * W4[tid*32 + j];
        out[b*2 + tid] = acc;
    }
}

extern "C" void kernel_launch(void* const* d_in, const int* in_sizes, int n_in,
                              void* d_out, int out_size, void* d_ws, size_t ws_size,
                              hipStream_t stream) {
    const float* xi   = (const float*)d_in[0];
    const float* Sw   = (const float*)d_in[1];
    const float* tmpl = (const float*)d_in[2];
    const float* hh   = (const float*)d_in[3];
    const float* W1   = (const float*)d_in[4];
    const float* b1   = (const float*)d_in[5];
    const float* W2   = (const float*)d_in[6];
    const float* b2   = (const float*)d_in[7];
    const float* W3   = (const float*)d_in[8];
    const float* b3   = (const float*)d_in[9];
    const float* W4   = (const float*)d_in[10];
    const float* b4   = (const float*)d_in[11];
    float* out = (float*)d_out;

    cf2* T16  = (cf2*)d_ws;                         // 16384 cf2 = 128 KB
    cf2* spec = T16 + 16384;                        // NSIG * SPEC_STRIDE cf2
    float* zarr = (float*)(spec + (size_t)NSIG * SPEC_STRIDE);

    // fwd grid: NSIG FFT blocks + 16 twiddle-table writer blocks (NT=1024).
    // W blocks write V = conj(W)*phase, so no premul kernel is needed.
    fwd_fft_kernel<<<dim3(NSIG + 16), dim3(NT), 0, stream>>>(xi, Sw, tmpl, T16, spec);
    inv_fft_kernel<<<dim3(BB * NTPL * 2), dim3(NT), 0, stream>>>(spec, T16, hh, zarr);
    head_kernel<<<dim3(BB), dim3(256), 0, stream>>>(zarr, W1, b1, W2, b2, W3, b3, W4, b4, out);
}

// Round 2
// 155.521 us; speedup vs baseline: 1.0437x; 1.0437x over previous
//
#include <hip/hip_runtime.h>
#include <math.h>

#define L_LEN 16384
#define M_LEN 8192
#define KT_LEN 4096
#define BB 32
#define NTPL 50
#define SPEC_STRIDE 8224   // complex slots per signal (>= 8193)
#define NSIG 166           // 64 x-signals + 2 w-signals + 100 templates
#define NTF 1024           // fwd block (radix-8 ladder, latency-bound regime)
#define NTI 512            // inv block (radix-16 ladder, issue-bound regime)
#define PI_F 3.14159265358979323846f
// cos/sin(pi/16): inv stage-3 twiddle base (radix-16 ladder)
#define C16 0.98078528040323044f
#define S16 0.19509032201612827f
// cos/sin(2*pi/16): fwd stage-4 twiddle base (radix-8 ladder)
#define C8 0.92387953251128674f
#define S8 0.38268343236508978f

typedef float cf2 __attribute__((ext_vector_type(2)));

// Lessons encoded in this structure:
//  R5: scattered per-lane twiddle table loads stall VMEM -> power chain from 1 load.
//  R6: XOR swizzle + cf2 packed math + algebraic per-stage indices = best layout.
//  R7: +1-per-32 pad layout TRIPLES bank conflicts vs XOR swizzle. Don't.
//  R8: __shfl_xor compiles to ds_bpermute (LDS pipe!) - shfl-based stage fusion
//      is slower than plain LDS stages + b128 final pass. Don't.
//  R9: radix-8/1024-thr doubled occupancy (36->72%) but VALUBusy stayed ~74%
//      and dur rose 69->75us (extra LDS pass + 3x bank conflicts). inv is
//      ISSUE-bound, not occupancy-bound. Keep radix-16 @512 for inv.
//      fwd (1 block/CU, latency-bound) DOES want 1024 threads: keep radix-8.
//  R10 (this round): cmul via VOP3P v_pk_mul_f32/v_pk_fma_f32 inline asm
//      (2 packed ops vs 4 scalar) to cut the dominant VALU issue stream.

// Packed complex multiply: 2 VOP3P instructions.
//  t = {a.x*b.x, a.x*b.y}              (op_sel_hi[0]=0 broadcasts a.x to hi)
//  d = {a.y*(-b.y)+t.lo, a.y*b.x+t.hi} (op_sel broadcast a.y, swap b, neg lo)
__device__ __forceinline__ cf2 cmul(cf2 a, cf2 b) {
    cf2 t, d;
    asm("v_pk_mul_f32 %0, %1, %2 op_sel:[0,0] op_sel_hi:[0,1]"
        : "=v"(t) : "v"(a), "v"(b));
    asm("v_pk_fma_f32 %0, %1, %2, %3 op_sel:[1,1,0] op_sel_hi:[1,0,1] neg_lo:[0,1,0]"
        : "=v"(d) : "v"(a), "v"(b), "v"(t));
    return d;
}
__device__ __forceinline__ cf2 cmulc(cf2 a, cf2 b) { // a * conj(b)
    return a * (cf2){b.x, b.x} + (cf2){a.y, -a.x} * (cf2){b.y, b.y};
}
template<int SIGN>
__device__ __forceinline__ cf2 rot90(cf2 z) {
    return (SIGN < 0) ? (cf2){z.y, -z.x} : (cf2){-z.y, z.x};
}
template<int SIGN>
__device__ __forceinline__ cf2 ldT(const cf2* __restrict__ T, int idx) {
    cf2 t = T[idx];
    if (SIGN > 0) t.y = -t.y;
    return t;
}

// LDS bank swizzle. Even XOR keeps float4 pair adjacency; involution.
__device__ __forceinline__ int swz(int i) { return i ^ (((i >> 5) & 15) << 1); }

// Digit reversal for fwd's radix 8,8,8,8,2 DIF ladder.
__device__ __forceinline__ int pos8(int f) {
    return ((f & 7) << 10) | (((f >> 3) & 7) << 7) |
           (((f >> 6) & 7) << 4) | (((f >> 9) & 7) << 1) | ((f >> 12) & 1);
}

// ---------------- radix-16 pieces (inv kernel) ----------------
template<int SIGN>
__device__ __forceinline__ void dft16(cf2 x[16]) {
    const float S = (SIGN < 0) ? -1.f : 1.f;
    const cf2 w1 = {0.9238795325112867f, S * 0.3826834323650898f};
    const cf2 w2 = {0.7071067811865476f, S * 0.7071067811865476f};
    const cf2 w3 = {0.3826834323650898f, S * 0.9238795325112867f};
    cf2 v[16];
    #pragma unroll
    for (int n1 = 0; n1 < 4; ++n1) {
        cf2 a0 = x[n1], a1 = x[n1+4], a2 = x[n1+8], a3 = x[n1+12];
        cf2 t0 = a0 + a2, t2 = a0 - a2;
        cf2 t1 = a1 + a3, t3 = rot90<SIGN>(a1 - a3);
        cf2 u0 = t0 + t1, u1 = t2 + t3;
        cf2 u2 = t0 - t1, u3 = t2 - t3;
        if (n1 == 1) { u1 = cmul(u1, w1); u2 = cmul(u2, w2); u3 = cmul(u3, w3); }
        else if (n1 == 2) { u1 = cmul(u1, w2); u2 = rot90<SIGN>(u2);
                            u3 = rot90<SIGN>(cmul(u3, w2)); }
        else if (n1 == 3) { u1 = cmul(u1, w3); u2 = rot90<SIGN>(cmul(u2, w2));
                            u3 = -cmul(u3, w1); }
        v[0*4+n1] = u0; v[1*4+n1] = u1; v[2*4+n1] = u2; v[3*4+n1] = u3;
    }
    #pragma unroll
    for (int r = 0; r < 4; ++r) {
        cf2 a0 = v[r*4+0], a1 = v[r*4+1], a2 = v[r*4+2], a3 = v[r*4+3];
        cf2 t0 = a0 + a2, t2 = a0 - a2;
        cf2 t1 = a1 + a3, t3 = rot90<SIGN>(a1 - a3);
        x[r]    = t0 + t1; x[r+4]  = t2 + t3;
        x[r+8]  = t0 - t1; x[r+12] = t2 - t3;
    }
}

template<int SIGN>
__device__ __forceinline__ void butterfly16(cf2* A, const int idx[16], cf2 w1) {
    cf2 x[16];
    #pragma unroll
    for (int n = 0; n < 16; ++n) x[n] = A[idx[n]];
    dft16<SIGN>(x);
    A[idx[0]] = x[0];
    A[idx[1]] = cmul(x[1], w1);
    const cf2 w2 = cmul(w1, w1);
    A[idx[2]] = cmul(x[2], w2);
    const cf2 w3 = cmul(w1, w2);
    A[idx[3]] = cmul(x[3], w3);
    const cf2 w4 = cmul(w2, w2);
    A[idx[4]] = cmul(x[4], w4);
    A[idx[5]] = cmul(x[5], cmul(w1, w4));
    A[idx[6]] = cmul(x[6], cmul(w2, w4));
    A[idx[7]] = cmul(x[7], cmul(w3, w4));
    const cf2 w8 = cmul(w4, w4);
    A[idx[8]]  = cmul(x[8],  w8);
    A[idx[9]]  = cmul(x[9],  cmul(w1, w8));
    A[idx[10]] = cmul(x[10], cmul(w2, w8));
    A[idx[11]] = cmul(x[11], cmul(w3, w8));
    const cf2 w12 = cmul(w4, w8);
    A[idx[12]] = cmul(x[12], w12);
    A[idx[13]] = cmul(x[13], cmul(w1, w12));
    A[idx[14]] = cmul(x[14], cmul(w2, w12));
    A[idx[15]] = cmul(x[15], cmul(w3, w12));
}

// ---------------- radix-8 pieces (fwd kernel) ----------------
template<int SIGN>
__device__ __forceinline__ void dft8(cf2 x[8]) {
    const float R2 = 0.70710678118654752f;
    const cf2 w81 = { R2, SIGN * R2 };
    const cf2 w83 = { -R2, SIGN * R2 };
    cf2 u0 = x[0] + x[4], u1 = x[1] + x[5], u2 = x[2] + x[6], u3 = x[3] + x[7];
    cf2 v0 = x[0] - x[4];
    cf2 v1 = cmul(x[1] - x[5], w81);
    cf2 v2 = rot90<SIGN>(x[2] - x[6]);
    cf2 v3 = cmul(x[3] - x[7], w83);
    cf2 t0 = u0 + u2, t2 = u0 - u2;
    cf2 t1 = u1 + u3, t3 = rot90<SIGN>(u1 - u3);
    x[0] = t0 + t1; x[2] = t2 + t3; x[4] = t0 - t1; x[6] = t2 - t3;
    cf2 s0 = v0 + v2, s2 = v0 - v2;
    cf2 s1 = v1 + v3, s3 = rot90<SIGN>(v1 - v3);
    x[1] = s0 + s1; x[3] = s2 + s3; x[5] = s0 - s1; x[7] = s2 - s3;
}

template<int SIGN>
__device__ __forceinline__ void butterfly8(cf2* A, const int idx[8], cf2 w1) {
    cf2 x[8];
    #pragma unroll
    for (int n = 0; n < 8; ++n) x[n] = A[idx[n]];
    dft8<SIGN>(x);
    A[idx[0]] = x[0];
    A[idx[1]] = cmul(x[1], w1);
    const cf2 w2 = cmul(w1, w1);
    A[idx[2]] = cmul(x[2], w2);
    const cf2 w3 = cmul(w1, w2);
    A[idx[3]] = cmul(x[3], w3);
    const cf2 w4 = cmul(w2, w2);
    A[idx[4]] = cmul(x[4], w4);
    A[idx[5]] = cmul(x[5], cmul(w1, w4));
    A[idx[6]] = cmul(x[6], cmul(w2, w4));
    A[idx[7]] = cmul(x[7], cmul(w3, w4));
}

// ---------------------------------------------------------------------------
// Kernel 1: forward real FFT (length 16384) via 8192-pt complex FFT.
// Radix 8,8,8,8,2 ladder, 1024 threads (R9: fwd is latency-bound at
// 1 block/CU -> wants max waves/block). Blocks [NSIG, NSIG+16) build the
// twiddle table T via quadrant-reduced float sincos. W blocks (sig 64/65)
// write V(f) = conj(W(f)) * e^{-i pi k/8192}, k = 4094*f mod 16384.
// ---------------------------------------------------------------------------
__global__ __launch_bounds__(NTF, 8)
void fwd_fft_kernel(const float* __restrict__ xi, const float* __restrict__ w,
                    const float* __restrict__ tmpl, cf2* __restrict__ Tw,
                    cf2* __restrict__ spec) {
    __shared__ __attribute__((aligned(16))) cf2 A[M_LEN];   // 64 KB
    const int sig = blockIdx.x;
    const int tid = threadIdx.x;

    if (sig >= NSIG) {   // twiddle writer: T[k] = e^{-2 pi i k / 16384}
        const int k = (sig - NSIG) * NTF + tid;
        const int quad = k >> 12, mm = k & 4095;
        float s, c; __sincosf(PI_F * (float)mm / 8192.f, &s, &c);
        cf2 v;   // (cos th, -sin th), th = pi k/8192 = quad*pi/2 + t
        if      (quad == 0) v = (cf2){ c, -s};
        else if (quad == 1) v = (cf2){-s, -c};
        else if (quad == 2) v = (cf2){-c,  s};
        else                v = (cf2){ s,  c};
        Tw[k] = v;
        return;
    }

    const float* src;
    int nre;
    if (sig < 64)      { src = xi   + sig * L_LEN;         nre = L_LEN; }
    else if (sig < 66) { src = w    + (sig - 64) * L_LEN;  nre = L_LEN; }
    else               { src = tmpl + (sig - 66) * KT_LEN; nre = KT_LEN; }
    const bool isW = (sig >= 64 && sig < 66);
    const int nc = nre >> 1;
    const float4* s4 = (const float4*)src;
    const int g0 = tid ^ ((tid >> 4) & 15);
    #pragma unroll
    for (int m = 0; m < 4; ++m) {
        const int u = 2*tid + 2048*m;
        float4 vv = (u < nc) ? s4[tid + 1024*m] : make_float4(0.f, 0.f, 0.f, 0.f);
        ((float4*)A)[g0 + 1024*m] = vv;
    }
    __syncthreads();

    {   // stage 1: stride 1024, w1 = W_8192^tid
        int idx[8]; const int b0 = swz(tid);
        #pragma unroll
        for (int n = 0; n < 8; ++n) idx[n] = b0 + 1024*n;
        float sn, cs; __sincosf(-PI_F * (float)(2*tid) / 8192.f, &sn, &cs);
        butterfly8<-1>(A, idx, (cf2){cs, sn});
    }
    __syncthreads();
    {   // stage 2: stride 128, w1 = W_1024^j
        const int blk = tid >> 7, j = tid & 127, jb = blk*1024;
        const int jsw = j ^ (((j >> 5) & 3) << 1);
        int idx[8];
        #pragma unroll
        for (int n = 0; n < 8; ++n) idx[n] = jb + 128*n + (jsw ^ ((n & 3) << 3));
        float sn, cs; __sincosf(-PI_F * (float)(16*j) / 8192.f, &sn, &cs);
        butterfly8<-1>(A, idx, (cf2){cs, sn});
    }
    __syncthreads();
    {   // stage 3: stride 16, w1 = W_128^j
        const int blk = tid >> 4, j = tid & 15;
        const int base = blk*128 + j, bx = (blk & 3) << 3;
        int idx[8];
        #pragma unroll
        for (int n = 0; n < 8; ++n) idx[n] = (base + 16*n) ^ bx ^ ((n >> 1) << 1);
        float sn, cs; __sincosf(-PI_F * (float)(128*j) / 8192.f, &sn, &cs);
        butterfly8<-1>(A, idx, (cf2){cs, sn});
    }
    __syncthreads();
    {   // stage 4: stride 2, w1 = W_16^j (constant)
        const int blk = tid >> 1, j = tid & 1;
        const int Xa = ((blk >> 1) & 15) << 1;
        const int base = ((blk << 4) | j) ^ (Xa & 16);
        const int xv = Xa & 14;
        int idx[8];
        #pragma unroll
        for (int n = 0; n < 8; ++n) idx[n] = base + ((2*n) ^ xv);
        cf2 w1 = j ? (cf2){C8, -S8} : (cf2){1.f, 0.f};
        butterfly8<-1>(A, idx, w1);
    }
    __syncthreads();
    // Final radix-2 (stride 1, no twiddle), b128 in-place.
    #pragma unroll
    for (int m = 0; m < 4; ++m) {
        float4 pq = ((float4*)A)[g0 + 1024*m];
        ((float4*)A)[g0 + 1024*m] = make_float4(pq.x + pq.z, pq.y + pq.w,
                                                pq.x - pq.z, pq.y - pq.w);
    }
    __syncthreads();

    // Untangle packed result to real-signal spectrum X[f], f = 0..M.
    cf2* out = spec + (size_t)sig * SPEC_STRIDE;
    #pragma unroll
    for (int m = 0; m < 8; ++m) {
        const int f = tid + 1024*m;
        const int fb = (M_LEN - f) & (M_LEN - 1);
        cf2 Za = A[swz(pos8(f))];
        cf2 Zb = A[swz(pos8(fb))];
        cf2 E = (cf2){0.5f*(Za.x + Zb.x), 0.5f*(Za.y - Zb.y)};
        cf2 D = (cf2){Za.x - Zb.x, Za.y + Zb.y};
        cf2 O = (cf2){0.5f*D.y, -0.5f*D.x};
        float sn, cs;
        __sincosf(-PI_F * (float)f / 8192.f, &sn, &cs);
        cf2 val = E + (cf2){cs*O.x - sn*O.y, cs*O.y + sn*O.x};
        if (isW) {   // V(f) = conj(W(f)) * e^{-i pi k/8192}, k exact int mod
            const int k = (4094 * f) & (L_LEN - 1);
            float psn, pcs; __sincosf(-PI_F * (float)k / 8192.f, &psn, &pcs);
            val = cmul((cf2){val.x, -val.y}, (cf2){pcs, psn});
        }
        out[f] = val;
    }
    if (tid == 0) {   // f = 8192
        cf2 Za = A[swz(0)];
        cf2 val = (cf2){Za.x - Za.y, 0.f};
        if (isW) {   // k(8192) = 8192 -> phase = (-1, 0)
            val = (cf2){-val.x, 0.f};
        }
        out[M_LEN] = val;
    }
}

// ---------------------------------------------------------------------------
// Kernel 2: per (b,n,c): S[f] = X[f]*V[f]*conj(H[f]); Hermitian pack fused
// into the product pass; 3 radix-16 LDS stages; final radix-2 fused with max.
// 512 threads, radix-16 (R9: issue-bound, radix-16 minimizes LDS passes).
// ---------------------------------------------------------------------------
__global__ __launch_bounds__(NTI, 4)
void inv_fft_kernel(const cf2* __restrict__ spec, const cf2* __restrict__ T,
                    const float* __restrict__ hh, float* __restrict__ zarr) {
    __shared__ __attribute__((aligned(16))) cf2 A[M_LEN];   // 64 KB
    const int idx0 = blockIdx.x;
    const int c = idx0 & 1;
    const int n = (idx0 >> 1) % NTPL;
    const int b = idx0 / (2 * NTPL);
    const int tid = threadIdx.x;

    const cf2* Xs = spec + (size_t)(b*2 + c)      * SPEC_STRIDE;
    const cf2* Vs = spec + (size_t)(64 + c)       * SPEC_STRIDE;
    const cf2* Hs = spec + (size_t)(66 + n*2 + c) * SPEC_STRIDE;
    const float4* X4 = (const float4*)Xs;
    const float4* V4 = (const float4*)Vs;
    const float4* H4 = (const float4*)Hs;
    const float4* T4 = (const float4*)T;
    const int g0 = tid ^ ((tid >> 4) & 15);

    // Fused product + Hermitian pack: thread t handles f = 2t+1024m+{0,1}
    // (f in [0,4096)) and partners 8192-f. Writes all of Z'[0..8191].
    #pragma unroll
    for (int m = 0; m < 4; ++m) {
        const int u = 2*tid + 1024*m;
        float4 xf = X4[tid + 512*m], vf = V4[tid + 512*m], hf = H4[tid + 512*m];
        cf2 Sa0 = cmulc(cmul((cf2){xf.x, xf.y}, (cf2){vf.x, vf.y}), (cf2){hf.x, hf.y});
        cf2 Sa1 = cmulc(cmul((cf2){xf.z, xf.w}, (cf2){vf.z, vf.w}), (cf2){hf.z, hf.w});
        cf2 Sb0 = cmulc(cmul(Xs[M_LEN - u],     Vs[M_LEN - u]),     Hs[M_LEN - u]);
        cf2 Sb1 = cmulc(cmul(Xs[M_LEN - 1 - u], Vs[M_LEN - 1 - u]), Hs[M_LEN - 1 - u]);
        float4 tw = T4[tid + 512*m];          // T[u], T[u+1]
        // f = u
        float cs0 = tw.x, sn0 = -tw.y;
        float Ex0 = 0.5f*(Sa0.x + Sb0.x), Ey0 = 0.5f*(Sa0.y - Sb0.y);
        float Dx0 = Sa0.x - Sb0.x,        Dy0 = Sa0.y + Sb0.y;
        float Ox0 = 0.5f*(cs0*Dx0 - sn0*Dy0), Oy0 = 0.5f*(cs0*Dy0 + sn0*Dx0);
        // f = u+1
        float cs1 = tw.z, sn1 = -tw.w;
        float Ex1 = 0.5f*(Sa1.x + Sb1.x), Ey1 = 0.5f*(Sa1.y - Sb1.y);
        float Dx1 = Sa1.x - Sb1.x,        Dy1 = Sa1.y + Sb1.y;
        float Ox1 = 0.5f*(cs1*Dx1 - sn1*Dy1), Oy1 = 0.5f*(cs1*Dy1 + sn1*Dx1);
        ((float4*)A)[g0 + 512*m] = make_float4(Ex0 - Oy0, Ey0 + Ox0,
                                               Ex1 - Oy1, Ey1 + Ox1);
        if (u > 0) A[swz(M_LEN - u)] = (cf2){Ex0 + Oy0, Ox0 - Ey0};
        A[swz(M_LEN - 1 - u)] = (cf2){Ex1 + Oy1, Ox1 - Ey1};
    }
    if (tid == 0) {   // f = 4096 (self-paired)
        cf2 S = cmulc(cmul(Xs[4096], Vs[4096]), Hs[4096]);
        A[swz(4096)] = (cf2){S.x, -S.y};
    }
    __syncthreads();

    {   // stage 1: stride 512, es = 2*tid
        int idx[16]; const int b0 = swz(tid);
        #pragma unroll
        for (int nn = 0; nn < 16; ++nn) idx[nn] = b0 + 512*nn;
        butterfly16<+1>(A, idx, ldT<+1>(T, 2*tid));
    }
    __syncthreads();
    {   // stage 2: stride 32, es = 32*j
        const int blk = tid >> 5, j = tid & 31, jb = blk*512;
        int idx[16];
        #pragma unroll
        for (int nn = 0; nn < 16; ++nn) idx[nn] = jb + 32*nn + (j ^ (2*nn));
        butterfly16<+1>(A, idx, ldT<+1>(T, 32*j));
    }
    __syncthreads();
    {   // stage 3: stride 2, es = 512*j
        const int blk = tid >> 1, j = tid & 1;
        const int xv = (blk & 15) << 1, b3 = blk*32 + j;
        int idx[16];
        #pragma unroll
        for (int nn = 0; nn < 16; ++nn) idx[nn] = b3 + ((2*nn) ^ xv);
        cf2 w1 = j ? (cf2){C16, S16} : (cf2){1.f, 0.f};
        butterfly16<+1>(A, idx, w1);
    }
    __syncthreads();

    // Final radix-2 fused with max over re/im of every time sample (b128).
    float mx = -INFINITY;
    #pragma unroll
    for (int m = 0; m < 8; ++m) {
        float4 pq = ((const float4*)A)[g0 + 512*m];
        mx = fmaxf(mx, fmaxf(fmaxf(pq.x + pq.z, pq.y + pq.w),
                             fmaxf(pq.x - pq.z, pq.y - pq.w)));
    }
    __syncthreads();   // all reads of A done before reusing it as scratch
    for (int off = 32; off > 0; off >>= 1)
        mx = fmaxf(mx, __shfl_xor(mx, off));
    const int lane = tid & 63, wv = tid >> 6;   // 8 waves
    float* redf = (float*)A;
    if (lane == 0) redf[wv] = mx;
    __syncthreads();
    if (tid == 0) {
        float mm = redf[0];
        for (int i = 1; i < NTI/64; ++i) mm = fmaxf(mm, redf[i]);
        zarr[(b*2 + c)*NTPL + n] = mm / ((float)M_LEN * hh[n*2 + c]);
    }
}

// ---------------------------------------------------------------------------
// Kernel 3: tiny CNN/MLP head. One block per batch element.
// ---------------------------------------------------------------------------
__global__ __launch_bounds__(256)
void head_kernel(const float* __restrict__ zarr,
                 const float* __restrict__ W1, const float* __restrict__ b1,
                 const float* __restrict__ W2, const float* __restrict__ b2,
                 const float* __restrict__ W3, const float* __restrict__ b3,
                 const float* __restrict__ W4, const float* __restrict__ b4,
                 float* __restrict__ out) {
    __shared__ float zl[2][NTPL];
    __shared__ float s1[16][48];
    __shared__ float p1[16][16];
    __shared__ float s2[32][14];
    __shared__ float hflat[128];
    __shared__ float h1[32];
    const int b = blockIdx.x, tid = threadIdx.x;

    for (int i = tid; i < 2*NTPL; i += 256) zl[i/NTPL][i%NTPL] = zarr[b*2*NTPL + i];
    __syncthreads();
    for (int i = tid; i < 16*48; i += 256) {
        const int o = i / 48, t = i % 48;
        float acc = b1[o];
        #pragma unroll
        for (int cc = 0; cc < 2; ++cc)
            #pragma unroll
            for (int k = 0; k < 3; ++k)
                acc += zl[cc][t+k] * W1[o*6 + cc*3 + k];
        s1[o][t] = 1.f / (1.f + __expf(-acc));
    }
    __syncthreads();
    for (int i = tid; i < 16*16; i += 256) {
        const int o = i / 16, u = i % 16;
        p1[o][u] = fmaxf(fmaxf(s1[o][3*u], s1[o][3*u+1]), s1[o][3*u+2]);
    }
    __syncthreads();
    for (int i = tid; i < 32*14; i += 256) {
        const int o = i / 14, t = i % 14;
        float acc = b2[o];
        for (int cc = 0; cc < 16; ++cc)
            #pragma unroll
            for (int k = 0; k < 3; ++k)
                acc += p1[cc][t+k] * W2[o*48 + cc*3 + k];
        s2[o][t] = 1.f / (1.f + __expf(-acc));
    }
    __syncthreads();
    for (int i = tid; i < 128; i += 256) {
        const int o = i / 4, u = i % 4;
        hflat[i] = fmaxf(fmaxf(s2[o][3*u], s2[o][3*u+1]), s2[o][3*u+2]);
    }
    __syncthreads();
    if (tid < 32) {
        float acc = b3[tid];
        for (int j = 0; j < 128; ++j) acc += hflat[j] * W3[tid*128 + j];
        h1[tid] = fmaxf(acc, 0.f);
    }
    __syncthreads();
    if (tid < 2) {
        float acc = b4[tid];
        for (int j = 0; j < 32; ++j) acc += h1[j] * W4[tid*32 + j];
        out[b*2 + tid] = acc;
    }
}

extern "C" void kernel_launch(void* const* d_in, const int* in_sizes, int n_in,
                              void* d_out, int out_size, void* d_ws, size_t ws_size,
                              hipStream_t stream) {
    const float* xi   = (const float*)d_in[0];
    const float* Sw   = (const float*)d_in[1];
    const float* tmpl = (const float*)d_in[2];
    const float* hh   = (const float*)d_in[3];
    const float* W1   = (const float*)d_in[4];
    const float* b1   = (const float*)d_in[5];
    const float* W2   = (const float*)d_in[6];
    const float* b2   = (const float*)d_in[7];
    const float* W3   = (const float*)d_in[8];
    const float* b3   = (const float*)d_in[9];
    const float* W4   = (const float*)d_in[10];
    const float* b4   = (const float*)d_in[11];
    float* out = (float*)d_out;

    cf2* T16  = (cf2*)d_ws;                         // 16384 cf2 = 128 KB
    cf2* spec = T16 + 16384;                        // NSIG * SPEC_STRIDE cf2
    float* zarr = (float*)(spec + (size_t)NSIG * SPEC_STRIDE);

    // fwd grid: NSIG FFT blocks + 16 twiddle-table writer blocks (NTF=1024).
    // W blocks write V = conj(W)*phase, so no premul kernel is needed.
    fwd_fft_kernel<<<dim3(NSIG + 16), dim3(NTF), 0, stream>>>(xi, Sw, tmpl, T16, spec);
    inv_fft_kernel<<<dim3(BB * NTPL * 2), dim3(NTI), 0, stream>>>(spec, T16, hh, zarr);
    head_kernel<<<dim3(BB), dim3(256), 0, stream>>>(zarr, W1, b1, W2, b2, W3, b3, W4, b4, out);
}

// Round 3
// 153.135 us; speedup vs baseline: 1.0599x; 1.0156x over previous
//
#include <hip/hip_runtime.h>
#include <math.h>

#define L_LEN 16384
#define M_LEN 8192
#define KT_LEN 4096
#define BB 32
#define NTPL 50
#define SPEC_STRIDE 8224   // complex slots per signal (>= 8193)
#define NSIG 166           // 64 x-signals + 2 w-signals + 100 templates
#define NTF 1024           // fwd block (radix-8 ladder, latency-bound regime)
#define NTI 512            // inv block (radix-16 ladder, issue-bound regime)
#define PI_F 3.14159265358979323846f
// cos/sin(pi/16): inv stage-3 twiddle base (radix-16 ladder)
#define C16 0.98078528040323044f
#define S16 0.19509032201612827f
// cos/sin(2*pi/16): fwd stage-4 twiddle base (radix-8 ladder)
#define C8 0.92387953251128674f
#define S8 0.38268343236508978f

typedef float cf2 __attribute__((ext_vector_type(2)));

// Lessons encoded in this structure:
//  R5: scattered per-lane twiddle table loads stall VMEM -> power chain from 1 load.
//  R6: XOR swizzle + cf2 packed math + algebraic per-stage indices = best layout.
//  R7: +1-per-32 pad layout TRIPLES bank conflicts vs XOR swizzle. Don't.
//  R8: __shfl_xor compiles to ds_bpermute (LDS pipe!) - shfl-based stage fusion
//      is slower than plain LDS stages + b128 final pass. Don't.
//  R9: radix-8/1024-thr doubled occupancy (36->72%) but VALUBusy stayed ~74%
//      and dur rose 69->75us. inv is ISSUE-bound, not occupancy-bound:
//      radix-16 @512 for inv; fwd (1 block/CU, latency-bound) keeps 1024-thr radix-8.
//  R10: cmul via VOP3P pk asm: VALUBusy 74->64%, inv 69->67.5us. Packed math
//      is the right lever; compiler does NOT form op_sel broadcasts itself.
//  R11 (this round): pk-ify the whole product/untangle pass (cmulc, Sp/Sm/R/
//      compose via neg_lo/neg_hi/op_sel) - 6 pk insts per point vs ~14 scalar.
//      0.5 factors dropped, folded into the final /(2*M*hh) scale.

// Packed complex multiply: 2 VOP3P instructions.
__device__ __forceinline__ cf2 cmul(cf2 a, cf2 b) {
    cf2 t, d;
    asm("v_pk_mul_f32 %0, %1, %2 op_sel:[0,0] op_sel_hi:[0,1]"
        : "=v"(t) : "v"(a), "v"(b));
    asm("v_pk_fma_f32 %0, %1, %2, %3 op_sel:[1,1,0] op_sel_hi:[1,0,1] neg_lo:[0,1,0]"
        : "=v"(d) : "v"(a), "v"(b), "v"(t));
    return d;
}
// a * conj(b): re = ax*bx + ay*by, im = ay*bx - ax*by. 2 VOP3P insts.
__device__ __forceinline__ cf2 cmulc(cf2 a, cf2 b) {
    cf2 t, d;
    asm("v_pk_mul_f32 %0, %1, %2 op_sel:[0,0] op_sel_hi:[0,1] neg_hi:[0,1]"
        : "=v"(t) : "v"(a), "v"(b));   // {ax*bx, -ax*by}
    asm("v_pk_fma_f32 %0, %1, %2, %3 op_sel:[1,1,0] op_sel_hi:[1,0,1]"
        : "=v"(d) : "v"(a), "v"(b), "v"(t));
    return d;
}
// conj(a) * b: re = ax*bx + ay*by, im = ax*by - ay*bx. 2 VOP3P insts.
__device__ __forceinline__ cf2 cmulca(cf2 a, cf2 b) {
    cf2 t, d;
    asm("v_pk_mul_f32 %0, %1, %2 op_sel:[0,0] op_sel_hi:[0,1]"
        : "=v"(t) : "v"(a), "v"(b));   // {ax*bx, ax*by}
    asm("v_pk_fma_f32 %0, %1, %2, %3 op_sel:[1,1,0] op_sel_hi:[1,0,1] neg_hi:[1,0,0]"
        : "=v"(d) : "v"(a), "v"(b), "v"(t));
    return d;
}
// {ax+bx, ay-by}
__device__ __forceinline__ cf2 pk_addch(cf2 a, cf2 b) {
    cf2 d;
    asm("v_pk_add_f32 %0, %1, %2 neg_hi:[0,1]" : "=v"(d) : "v"(a), "v"(b));
    return d;
}
// {ax-bx, ay+by}
__device__ __forceinline__ cf2 pk_subcl(cf2 a, cf2 b) {
    cf2 d;
    asm("v_pk_add_f32 %0, %1, %2 neg_lo:[0,1]" : "=v"(d) : "v"(a), "v"(b));
    return d;
}
// {s.x - r.y, s.y + r.x}  (= s + i*r)
__device__ __forceinline__ cf2 pk_compose1(cf2 s, cf2 r) {
    cf2 d;
    asm("v_pk_add_f32 %0, %1, %2 op_sel:[0,1] op_sel_hi:[0,0] neg_lo:[0,1]"
        : "=v"(d) : "v"(s), "v"(r));
    return d;
}
// {s.x + r.y, r.x - s.y}  (= conj(s - i*r))
__device__ __forceinline__ cf2 pk_compose2(cf2 s, cf2 r) {
    cf2 d;
    asm("v_pk_add_f32 %0, %1, %2 op_sel:[0,1] op_sel_hi:[0,0] neg_hi:[1,0]"
        : "=v"(d) : "v"(s), "v"(r));
    return d;
}
template<int SIGN>
__device__ __forceinline__ cf2 rot90(cf2 z) {
    return (SIGN < 0) ? (cf2){z.y, -z.x} : (cf2){-z.y, z.x};
}
template<int SIGN>
__device__ __forceinline__ cf2 ldT(const cf2* __restrict__ T, int idx) {
    cf2 t = T[idx];
    if (SIGN > 0) t.y = -t.y;
    return t;
}

// LDS bank swizzle. Even XOR keeps float4 pair adjacency; involution.
__device__ __forceinline__ int swz(int i) { return i ^ (((i >> 5) & 15) << 1); }

// Digit reversal for fwd's radix 8,8,8,8,2 DIF ladder.
__device__ __forceinline__ int pos8(int f) {
    return ((f & 7) << 10) | (((f >> 3) & 7) << 7) |
           (((f >> 6) & 7) << 4) | (((f >> 9) & 7) << 1) | ((f >> 12) & 1);
}

// ---------------- radix-16 pieces (inv kernel) ----------------
template<int SIGN>
__device__ __forceinline__ void dft16(cf2 x[16]) {
    const float S = (SIGN < 0) ? -1.f : 1.f;
    const cf2 w1 = {0.9238795325112867f, S * 0.3826834323650898f};
    const cf2 w2 = {0.7071067811865476f, S * 0.7071067811865476f};
    const cf2 w3 = {0.3826834323650898f, S * 0.9238795325112867f};
    cf2 v[16];
    #pragma unroll
    for (int n1 = 0; n1 < 4; ++n1) {
        cf2 a0 = x[n1], a1 = x[n1+4], a2 = x[n1+8], a3 = x[n1+12];
        cf2 t0 = a0 + a2, t2 = a0 - a2;
        cf2 t1 = a1 + a3, t3 = rot90<SIGN>(a1 - a3);
        cf2 u0 = t0 + t1, u1 = t2 + t3;
        cf2 u2 = t0 - t1, u3 = t2 - t3;
        if (n1 == 1) { u1 = cmul(u1, w1); u2 = cmul(u2, w2); u3 = cmul(u3, w3); }
        else if (n1 == 2) { u1 = cmul(u1, w2); u2 = rot90<SIGN>(u2);
                            u3 = rot90<SIGN>(cmul(u3, w2)); }
        else if (n1 == 3) { u1 = cmul(u1, w3); u2 = rot90<SIGN>(cmul(u2, w2));
                            u3 = -cmul(u3, w1); }
        v[0*4+n1] = u0; v[1*4+n1] = u1; v[2*4+n1] = u2; v[3*4+n1] = u3;
    }
    #pragma unroll
    for (int r = 0; r < 4; ++r) {
        cf2 a0 = v[r*4+0], a1 = v[r*4+1], a2 = v[r*4+2], a3 = v[r*4+3];
        cf2 t0 = a0 + a2, t2 = a0 - a2;
        cf2 t1 = a1 + a3, t3 = rot90<SIGN>(a1 - a3);
        x[r]    = t0 + t1; x[r+4]  = t2 + t3;
        x[r+8]  = t0 - t1; x[r+12] = t2 - t3;
    }
}

template<int SIGN>
__device__ __forceinline__ void butterfly16(cf2* A, const int idx[16], cf2 w1) {
    cf2 x[16];
    #pragma unroll
    for (int n = 0; n < 16; ++n) x[n] = A[idx[n]];
    dft16<SIGN>(x);
    A[idx[0]] = x[0];
    A[idx[1]] = cmul(x[1], w1);
    const cf2 w2 = cmul(w1, w1);
    A[idx[2]] = cmul(x[2], w2);
    const cf2 w3 = cmul(w1, w2);
    A[idx[3]] = cmul(x[3], w3);
    const cf2 w4 = cmul(w2, w2);
    A[idx[4]] = cmul(x[4], w4);
    A[idx[5]] = cmul(x[5], cmul(w1, w4));
    A[idx[6]] = cmul(x[6], cmul(w2, w4));
    A[idx[7]] = cmul(x[7], cmul(w3, w4));
    const cf2 w8 = cmul(w4, w4);
    A[idx[8]]  = cmul(x[8],  w8);
    A[idx[9]]  = cmul(x[9],  cmul(w1, w8));
    A[idx[10]] = cmul(x[10], cmul(w2, w8));
    A[idx[11]] = cmul(x[11], cmul(w3, w8));
    const cf2 w12 = cmul(w4, w8);
    A[idx[12]] = cmul(x[12], w12);
    A[idx[13]] = cmul(x[13], cmul(w1, w12));
    A[idx[14]] = cmul(x[14], cmul(w2, w12));
    A[idx[15]] = cmul(x[15], cmul(w3, w12));
}

// ---------------- radix-8 pieces (fwd kernel) ----------------
template<int SIGN>
__device__ __forceinline__ void dft8(cf2 x[8]) {
    const float R2 = 0.70710678118654752f;
    const cf2 w81 = { R2, SIGN * R2 };
    const cf2 w83 = { -R2, SIGN * R2 };
    cf2 u0 = x[0] + x[4], u1 = x[1] + x[5], u2 = x[2] + x[6], u3 = x[3] + x[7];
    cf2 v0 = x[0] - x[4];
    cf2 v1 = cmul(x[1] - x[5], w81);
    cf2 v2 = rot90<SIGN>(x[2] - x[6]);
    cf2 v3 = cmul(x[3] - x[7], w83);
    cf2 t0 = u0 + u2, t2 = u0 - u2;
    cf2 t1 = u1 + u3, t3 = rot90<SIGN>(u1 - u3);
    x[0] = t0 + t1; x[2] = t2 + t3; x[4] = t0 - t1; x[6] = t2 - t3;
    cf2 s0 = v0 + v2, s2 = v0 - v2;
    cf2 s1 = v1 + v3, s3 = rot90<SIGN>(v1 - v3);
    x[1] = s0 + s1; x[3] = s2 + s3; x[5] = s0 - s1; x[7] = s2 - s3;
}

template<int SIGN>
__device__ __forceinline__ void butterfly8(cf2* A, const int idx[8], cf2 w1) {
    cf2 x[8];
    #pragma unroll
    for (int n = 0; n < 8; ++n) x[n] = A[idx[n]];
    dft8<SIGN>(x);
    A[idx[0]] = x[0];
    A[idx[1]] = cmul(x[1], w1);
    const cf2 w2 = cmul(w1, w1);
    A[idx[2]] = cmul(x[2], w2);
    const cf2 w3 = cmul(w1, w2);
    A[idx[3]] = cmul(x[3], w3);
    const cf2 w4 = cmul(w2, w2);
    A[idx[4]] = cmul(x[4], w4);
    A[idx[5]] = cmul(x[5], cmul(w1, w4));
    A[idx[6]] = cmul(x[6], cmul(w2, w4));
    A[idx[7]] = cmul(x[7], cmul(w3, w4));
}

// ---------------------------------------------------------------------------
// Kernel 1: forward real FFT (length 16384) via 8192-pt complex FFT.
// Radix 8,8,8,8,2 ladder, 1024 threads (R9). Blocks [NSIG, NSIG+16) build the
// twiddle table T via quadrant-reduced float sincos. W blocks (sig 64/65)
// write V(f) = conj(W(f)) * e^{-i pi k/8192}, k = 4094*f mod 16384.
// ---------------------------------------------------------------------------
__global__ __launch_bounds__(NTF, 8)
void fwd_fft_kernel(const float* __restrict__ xi, const float* __restrict__ w,
                    const float* __restrict__ tmpl, cf2* __restrict__ Tw,
                    cf2* __restrict__ spec) {
    __shared__ __attribute__((aligned(16))) cf2 A[M_LEN];   // 64 KB
    const int sig = blockIdx.x;
    const int tid = threadIdx.x;

    if (sig >= NSIG) {   // twiddle writer: T[k] = e^{-2 pi i k / 16384}
        const int k = (sig - NSIG) * NTF + tid;
        const int quad = k >> 12, mm = k & 4095;
        float s, c; __sincosf(PI_F * (float)mm / 8192.f, &s, &c);
        cf2 v;   // (cos th, -sin th), th = pi k/8192 = quad*pi/2 + t
        if      (quad == 0) v = (cf2){ c, -s};
        else if (quad == 1) v = (cf2){-s, -c};
        else if (quad == 2) v = (cf2){-c,  s};
        else                v = (cf2){ s,  c};
        Tw[k] = v;
        return;
    }

    const float* src;
    int nre;
    if (sig < 64)      { src = xi   + sig * L_LEN;         nre = L_LEN; }
    else if (sig < 66) { src = w    + (sig - 64) * L_LEN;  nre = L_LEN; }
    else               { src = tmpl + (sig - 66) * KT_LEN; nre = KT_LEN; }
    const bool isW = (sig >= 64 && sig < 66);
    const int nc = nre >> 1;
    const float4* s4 = (const float4*)src;
    const int g0 = tid ^ ((tid >> 4) & 15);
    #pragma unroll
    for (int m = 0; m < 4; ++m) {
        const int u = 2*tid + 2048*m;
        float4 vv = (u < nc) ? s4[tid + 1024*m] : make_float4(0.f, 0.f, 0.f, 0.f);
        ((float4*)A)[g0 + 1024*m] = vv;
    }
    __syncthreads();

    {   // stage 1: stride 1024, w1 = W_8192^tid
        int idx[8]; const int b0 = swz(tid);
        #pragma unroll
        for (int n = 0; n < 8; ++n) idx[n] = b0 + 1024*n;
        float sn, cs; __sincosf(-PI_F * (float)(2*tid) / 8192.f, &sn, &cs);
        butterfly8<-1>(A, idx, (cf2){cs, sn});
    }
    __syncthreads();
    {   // stage 2: stride 128, w1 = W_1024^j
        const int blk = tid >> 7, j = tid & 127, jb = blk*1024;
        const int jsw = j ^ (((j >> 5) & 3) << 1);
        int idx[8];
        #pragma unroll
        for (int n = 0; n < 8; ++n) idx[n] = jb + 128*n + (jsw ^ ((n & 3) << 3));
        float sn, cs; __sincosf(-PI_F * (float)(16*j) / 8192.f, &sn, &cs);
        butterfly8<-1>(A, idx, (cf2){cs, sn});
    }
    __syncthreads();
    {   // stage 3: stride 16, w1 = W_128^j
        const int blk = tid >> 4, j = tid & 15;
        const int base = blk*128 + j, bx = (blk & 3) << 3;
        int idx[8];
        #pragma unroll
        for (int n = 0; n < 8; ++n) idx[n] = (base + 16*n) ^ bx ^ ((n >> 1) << 1);
        float sn, cs; __sincosf(-PI_F * (float)(128*j) / 8192.f, &sn, &cs);
        butterfly8<-1>(A, idx, (cf2){cs, sn});
    }
    __syncthreads();
    {   // stage 4: stride 2, w1 = W_16^j (constant)
        const int blk = tid >> 1, j = tid & 1;
        const int Xa = ((blk >> 1) & 15) << 1;
        const int base = ((blk << 4) | j) ^ (Xa & 16);
        const int xv = Xa & 14;
        int idx[8];
        #pragma unroll
        for (int n = 0; n < 8; ++n) idx[n] = base + ((2*n) ^ xv);
        cf2 w1 = j ? (cf2){C8, -S8} : (cf2){1.f, 0.f};
        butterfly8<-1>(A, idx, w1);
    }
    __syncthreads();
    // Final radix-2 (stride 1, no twiddle), b128 in-place.
    #pragma unroll
    for (int m = 0; m < 4; ++m) {
        float4 pq = ((float4*)A)[g0 + 1024*m];
        ((float4*)A)[g0 + 1024*m] = make_float4(pq.x + pq.z, pq.y + pq.w,
                                                pq.x - pq.z, pq.y - pq.w);
    }
    __syncthreads();

    // Untangle packed result to real-signal spectrum X[f], f = 0..M.
    cf2* out = spec + (size_t)sig * SPEC_STRIDE;
    #pragma unroll
    for (int m = 0; m < 8; ++m) {
        const int f = tid + 1024*m;
        const int fb = (M_LEN - f) & (M_LEN - 1);
        cf2 Za = A[swz(pos8(f))];
        cf2 Zb = A[swz(pos8(fb))];
        cf2 E = (cf2){0.5f*(Za.x + Zb.x), 0.5f*(Za.y - Zb.y)};
        cf2 D = (cf2){Za.x - Zb.x, Za.y + Zb.y};
        cf2 O = (cf2){0.5f*D.y, -0.5f*D.x};
        float sn, cs;
        __sincosf(-PI_F * (float)f / 8192.f, &sn, &cs);
        cf2 val = E + (cf2){cs*O.x - sn*O.y, cs*O.y + sn*O.x};
        if (isW) {   // V(f) = conj(W(f)) * e^{-i pi k/8192}, k exact int mod
            const int k = (4094 * f) & (L_LEN - 1);
            float psn, pcs; __sincosf(-PI_F * (float)k / 8192.f, &psn, &pcs);
            val = cmul((cf2){val.x, -val.y}, (cf2){pcs, psn});
        }
        out[f] = val;
    }
    if (tid == 0) {   // f = 8192
        cf2 Za = A[swz(0)];
        cf2 val = (cf2){Za.x - Za.y, 0.f};
        if (isW) {   // k(8192) = 8192 -> phase = (-1, 0)
            val = (cf2){-val.x, 0.f};
        }
        out[M_LEN] = val;
    }
}

// ---------------------------------------------------------------------------
// Kernel 2: per (b,n,c): S[f] = X[f]*V[f]*conj(H[f]); Hermitian pack fused
// into the product pass (fully VOP3P-packed, R11; 2x scale folded into the
// final divide); 3 radix-16 LDS stages; final radix-2 fused with max.
// ---------------------------------------------------------------------------
__global__ __launch_bounds__(NTI, 4)
void inv_fft_kernel(const cf2* __restrict__ spec, const cf2* __restrict__ T,
                    const float* __restrict__ hh, float* __restrict__ zarr) {
    __shared__ __attribute__((aligned(16))) cf2 A[M_LEN];   // 64 KB
    const int idx0 = blockIdx.x;
    const int c = idx0 & 1;
    const int n = (idx0 >> 1) % NTPL;
    const int b = idx0 / (2 * NTPL);
    const int tid = threadIdx.x;

    const cf2* Xs = spec + (size_t)(b*2 + c)      * SPEC_STRIDE;
    const cf2* Vs = spec + (size_t)(64 + c)       * SPEC_STRIDE;
    const cf2* Hs = spec + (size_t)(66 + n*2 + c) * SPEC_STRIDE;
    const float4* X4 = (const float4*)Xs;
    const float4* V4 = (const float4*)Vs;
    const float4* H4 = (const float4*)Hs;
    const float4* T4 = (const float4*)T;
    const int g0 = tid ^ ((tid >> 4) & 15);

    // Fused product + Hermitian pack, all VOP3P. Thread t handles f =
    // 2t+1024m+{0,1} (f in [0,4096)) and partners 8192-f. Z' entries carry a
    // uniform 2x scale vs the exact pack (0.5 dropped); the self-paired f=4096
    // entry is doubled to match; the final zarr divide uses 2*M_LEN.
    #pragma unroll
    for (int m = 0; m < 4; ++m) {
        const int u = 2*tid + 1024*m;
        float4 xf = X4[tid + 512*m], vf = V4[tid + 512*m], hf = H4[tid + 512*m];
        cf2 P0 = cmulc(cmul((cf2){xf.x, xf.y}, (cf2){vf.x, vf.y}), (cf2){hf.x, hf.y});
        cf2 P1 = cmulc(cmul((cf2){xf.z, xf.w}, (cf2){vf.z, vf.w}), (cf2){hf.z, hf.w});
        cf2 Q0 = cmulc(cmul(Xs[M_LEN - u],     Vs[M_LEN - u]),     Hs[M_LEN - u]);
        cf2 Q1 = cmulc(cmul(Xs[M_LEN - 1 - u], Vs[M_LEN - 1 - u]), Hs[M_LEN - 1 - u]);
        float4 tw = T4[tid + 512*m];          // T[u], T[u+1]
        cf2 t0 = (cf2){tw.x, tw.y}, t1 = (cf2){tw.z, tw.w};
        // f = u:    Sp = P + conj(Q); Sm = P - conj(Q); R = conj(T[u]) * Sm
        cf2 Sp0 = pk_addch(P0, Q0), Sm0 = pk_subcl(P0, Q0);
        cf2 R0 = cmulca(t0, Sm0);
        // f = u+1
        cf2 Sp1 = pk_addch(P1, Q1), Sm1 = pk_subcl(P1, Q1);
        cf2 R1 = cmulca(t1, Sm1);
        cf2 Z0 = pk_compose1(Sp0, R0);        // Z'[u]     = Sp + i*R
        cf2 Z1 = pk_compose1(Sp1, R1);
        ((float4*)A)[g0 + 512*m] = make_float4(Z0.x, Z0.y, Z1.x, Z1.y);
        if (u > 0) A[swz(M_LEN - u)] = pk_compose2(Sp0, R0);  // conj(Sp - i*R)
        A[swz(M_LEN - 1 - u)] = pk_compose2(Sp1, R1);
    }
    if (tid == 0) {   // f = 4096 (self-paired), doubled to match the 2x scale
        cf2 S = cmulc(cmul(Xs[4096], Vs[4096]), Hs[4096]);
        A[swz(4096)] = (cf2){2.f * S.x, -2.f * S.y};
    }
    __syncthreads();

    {   // stage 1: stride 512, es = 2*tid
        int idx[16]; const int b0 = swz(tid);
        #pragma unroll
        for (int nn = 0; nn < 16; ++nn) idx[nn] = b0 + 512*nn;
        butterfly16<+1>(A, idx, ldT<+1>(T, 2*tid));
    }
    __syncthreads();
    {   // stage 2: stride 32, es = 32*j
        const int blk = tid >> 5, j = tid & 31, jb = blk*512;
        int idx[16];
        #pragma unroll
        for (int nn = 0; nn < 16; ++nn) idx[nn] = jb + 32*nn + (j ^ (2*nn));
        butterfly16<+1>(A, idx, ldT<+1>(T, 32*j));
    }
    __syncthreads();
    {   // stage 3: stride 2, es = 512*j
        const int blk = tid >> 1, j = tid & 1;
        const int xv = (blk & 15) << 1, b3 = blk*32 + j;
        int idx[16];
        #pragma unroll
        for (int nn = 0; nn < 16; ++nn) idx[nn] = b3 + ((2*nn) ^ xv);
        cf2 w1 = j ? (cf2){C16, S16} : (cf2){1.f, 0.f};
        butterfly16<+1>(A, idx, w1);
    }
    __syncthreads();

    // Final radix-2 fused with max over re/im of every time sample (b128).
    float mx = -INFINITY;
    #pragma unroll
    for (int m = 0; m < 8; ++m) {
        float4 pq = ((const float4*)A)[g0 + 512*m];
        mx = fmaxf(mx, fmaxf(fmaxf(pq.x + pq.z, pq.y + pq.w),
                             fmaxf(pq.x - pq.z, pq.y - pq.w)));
    }
    __syncthreads();   // all reads of A done before reusing it as scratch
    for (int off = 32; off > 0; off >>= 1)
        mx = fmaxf(mx, __shfl_xor(mx, off));
    const int lane = tid & 63, wv = tid >> 6;   // 8 waves
    float* redf = (float*)A;
    if (lane == 0) redf[wv] = mx;
    __syncthreads();
    if (tid == 0) {
        float mm = redf[0];
        for (int i = 1; i < NTI/64; ++i) mm = fmaxf(mm, redf[i]);
        zarr[(b*2 + c)*NTPL + n] = mm / (2.f * (float)M_LEN * hh[n*2 + c]);
    }
}

// ---------------------------------------------------------------------------
// Kernel 3: tiny CNN/MLP head. One block per batch element.
// ---------------------------------------------------------------------------
__global__ __launch_bounds__(256)
void head_kernel(const float* __restrict__ zarr,
                 const float* __restrict__ W1, const float* __restrict__ b1,
                 const float* __restrict__ W2, const float* __restrict__ b2,
                 const float* __restrict__ W3, const float* __restrict__ b3,
                 const float* __restrict__ W4, const float* __restrict__ b4,
                 float* __restrict__ out) {
    __shared__ float zl[2][NTPL];
    __shared__ float s1[16][48];
    __shared__ float p1[16][16];
    __shared__ float s2[32][14];
    __shared__ float hflat[128];
    __shared__ float h1[32];
    const int b = blockIdx.x, tid = threadIdx.x;

    for (int i = tid; i < 2*NTPL; i += 256) zl[i/NTPL][i%NTPL] = zarr[b*2*NTPL + i];
    __syncthreads();
    for (int i = tid; i < 16*48; i += 256) {
        const int o = i / 48, t = i % 48;
        float acc = b1[o];
        #pragma unroll
        for (int cc = 0; cc < 2; ++cc)
            #pragma unroll
            for (int k = 0; k < 3; ++k)
                acc += zl[cc][t+k] * W1[o*6 + cc*3 + k];
        s1[o][t] = 1.f / (1.f + __expf(-acc));
    }
    __syncthreads();
    for (int i = tid; i < 16*16; i += 256) {
        const int o = i / 16, u = i % 16;
        p1[o][u] = fmaxf(fmaxf(s1[o][3*u], s1[o][3*u+1]), s1[o][3*u+2]);
    }
    __syncthreads();
    for (int i = tid; i < 32*14; i += 256) {
        const int o = i / 14, t = i % 14;
        float acc = b2[o];
        for (int cc = 0; cc < 16; ++cc)
            #pragma unroll
            for (int k = 0; k < 3; ++k)
                acc += p1[cc][t+k] * W2[o*48 + cc*3 + k];
        s2[o][t] = 1.f / (1.f + __expf(-acc));
    }
    __syncthreads();
    for (int i = tid; i < 128; i += 256) {
        const int o = i / 4, u = i % 4;
        hflat[i] = fmaxf(fmaxf(s2[o][3*u], s2[o][3*u+1]), s2[o][3*u+2]);
    }
    __syncthreads();
    if (tid < 32) {
        float acc = b3[tid];
        for (int j = 0; j < 128; ++j) acc += hflat[j] * W3[tid*128 + j];
        h1[tid] = fmaxf(acc, 0.f);
    }
    __syncthreads();
    if (tid < 2) {
        float acc = b4[tid];
        for (int j = 0; j < 32; ++j) acc += h1[j] * W4[tid*32 + j];
        out[b*2 + tid] = acc;
    }
}

extern "C" void kernel_launch(void* const* d_in, const int* in_sizes, int n_in,
                              void* d_out, int out_size, void* d_ws, size_t ws_size,
                              hipStream_t stream) {
    const float* xi   = (const float*)d_in[0];
    const float* Sw   = (const float*)d_in[1];
    const float* tmpl = (const float*)d_in[2];
    const float* hh   = (const float*)d_in[3];
    const float* W1   = (const float*)d_in[4];
    const float* b1   = (const float*)d_in[5];
    const float* W2   = (const float*)d_in[6];
    const float* b2   = (const float*)d_in[7];
    const float* W3   = (const float*)d_in[8];
    const float* b3   = (const float*)d_in[9];
    const float* W4   = (const float*)d_in[10];
    const float* b4   = (const float*)d_in[11];
    float* out = (float*)d_out;

    cf2* T16  = (cf2*)d_ws;                         // 16384 cf2 = 128 KB
    cf2* spec = T16 + 16384;                        // NSIG * SPEC_STRIDE cf2
    float* zarr = (float*)(spec + (size_t)NSIG * SPEC_STRIDE);

    // fwd grid: NSIG FFT blocks + 16 twiddle-table writer blocks (NTF=1024).
    // W blocks write V = conj(W)*phase, so no premul kernel is needed.
    fwd_fft_kernel<<<dim3(NSIG + 16), dim3(NTF), 0, stream>>>(xi, Sw, tmpl, T16, spec);
    inv_fft_kernel<<<dim3(BB * NTPL * 2), dim3(NTI), 0, stream>>>(spec, T16, hh, zarr);
    head_kernel<<<dim3(BB), dim3(256), 0, stream>>>(zarr, W1, b1, W2, b2, W3, b3, W4, b4, out);
}

// Round 4
// 152.977 us; speedup vs baseline: 1.0610x; 1.0010x over previous
//
#include <hip/hip_runtime.h>
#include <math.h>

#define L_LEN 16384
#define M_LEN 8192
#define KT_LEN 4096
#define BB 32
#define NTPL 50
#define SPEC_STRIDE 8224   // complex slots per signal (>= 8193)
#define NSIG 166           // 64 x-signals + 2 w-signals + 100 templates
#define NTF 1024           // fwd block (radix-8 ladder, latency-bound regime)
#define NTI 512            // inv block (radix-16 ladder, issue-bound regime)
#define PI_F 3.14159265358979323846f
// cos/sin(pi/16): inv stage-3 twiddle base (radix-16 ladder)
#define C16 0.98078528040323044f
#define S16 0.19509032201612827f
// cos/sin(2*pi/16): fwd stage-4 twiddle base (radix-8 ladder)
#define C8 0.92387953251128674f
#define S8 0.38268343236508978f

typedef float cf2 __attribute__((ext_vector_type(2)));

// Lessons encoded in this structure:
//  R5: scattered per-lane twiddle table loads stall VMEM -> power chain from 1 load.
//  R6: XOR swizzle + cf2 packed math + algebraic per-stage indices = best layout.
//  R7: +1-per-32 pad layout TRIPLES bank conflicts vs XOR swizzle (FFT tiles).
//  R8: __shfl_xor compiles to ds_bpermute (LDS pipe!) - shfl-based stage fusion
//      is slower than plain LDS stages + b128 final pass. Don't.
//  R9: radix-8/1024-thr doubled occupancy (36->72%) but VALUBusy stayed ~74%
//      and dur rose 69->75us. inv is ISSUE-bound, not occupancy-bound:
//      radix-16 @512 for inv; fwd (1 block/CU, latency-bound) keeps 1024-thr radix-8.
//  R10: cmul via VOP3P pk asm: VALUBusy 74->64%, inv 69->67.5us. Packed math
//      is the right lever; compiler does NOT form op_sel broadcasts itself.
//  R11: pk-ified product/untangle pass: VALU 64->58.6%, inv 67.5->65.2us.
//      inv now co-saturated VALU~LDS~58% - structure near log16 minimum.
//  R12 (this round): head_kernel was latency-bound: fc1 = 32 threads (half a
//      wave) x 128 rolled dependent GLOBAL loads; conv2 = 48 rolled global
//      loads/output. Fix: stage all weights in LDS (W3 padded stride 132,
//      <=2-way banks on fc1 pattern), unroll all MAC loops, fc1 as 32x8 lanes
//      + shfl_xor tree. fwd launch bound 8->4 waves/EU (grid 182 = 1 block/CU
//      resident anyway; the 8/EU bound only capped VGPR at 64 for nothing).

// Packed complex multiply: 2 VOP3P instructions.
__device__ __forceinline__ cf2 cmul(cf2 a, cf2 b) {
    cf2 t, d;
    asm("v_pk_mul_f32 %0, %1, %2 op_sel:[0,0] op_sel_hi:[0,1]"
        : "=v"(t) : "v"(a), "v"(b));
    asm("v_pk_fma_f32 %0, %1, %2, %3 op_sel:[1,1,0] op_sel_hi:[1,0,1] neg_lo:[0,1,0]"
        : "=v"(d) : "v"(a), "v"(b), "v"(t));
    return d;
}
// a * conj(b): re = ax*bx + ay*by, im = ay*bx - ax*by. 2 VOP3P insts.
__device__ __forceinline__ cf2 cmulc(cf2 a, cf2 b) {
    cf2 t, d;
    asm("v_pk_mul_f32 %0, %1, %2 op_sel:[0,0] op_sel_hi:[0,1] neg_hi:[0,1]"
        : "=v"(t) : "v"(a), "v"(b));   // {ax*bx, -ax*by}
    asm("v_pk_fma_f32 %0, %1, %2, %3 op_sel:[1,1,0] op_sel_hi:[1,0,1]"
        : "=v"(d) : "v"(a), "v"(b), "v"(t));
    return d;
}
// conj(a) * b: re = ax*bx + ay*by, im = ax*by - ay*bx. 2 VOP3P insts.
__device__ __forceinline__ cf2 cmulca(cf2 a, cf2 b) {
    cf2 t, d;
    asm("v_pk_mul_f32 %0, %1, %2 op_sel:[0,0] op_sel_hi:[0,1]"
        : "=v"(t) : "v"(a), "v"(b));   // {ax*bx, ax*by}
    asm("v_pk_fma_f32 %0, %1, %2, %3 op_sel:[1,1,0] op_sel_hi:[1,0,1] neg_hi:[1,0,0]"
        : "=v"(d) : "v"(a), "v"(b), "v"(t));
    return d;
}
// {ax+bx, ay-by}
__device__ __forceinline__ cf2 pk_addch(cf2 a, cf2 b) {
    cf2 d;
    asm("v_pk_add_f32 %0, %1, %2 neg_hi:[0,1]" : "=v"(d) : "v"(a), "v"(b));
    return d;
}
// {ax-bx, ay+by}
__device__ __forceinline__ cf2 pk_subcl(cf2 a, cf2 b) {
    cf2 d;
    asm("v_pk_add_f32 %0, %1, %2 neg_lo:[0,1]" : "=v"(d) : "v"(a), "v"(b));
    return d;
}
// {s.x - r.y, s.y + r.x}  (= s + i*r)
__device__ __forceinline__ cf2 pk_compose1(cf2 s, cf2 r) {
    cf2 d;
    asm("v_pk_add_f32 %0, %1, %2 op_sel:[0,1] op_sel_hi:[0,0] neg_lo:[0,1]"
        : "=v"(d) : "v"(s), "v"(r));
    return d;
}
// {s.x + r.y, r.x - s.y}  (= conj(s - i*r))
__device__ __forceinline__ cf2 pk_compose2(cf2 s, cf2 r) {
    cf2 d;
    asm("v_pk_add_f32 %0, %1, %2 op_sel:[0,1] op_sel_hi:[0,0] neg_hi:[1,0]"
        : "=v"(d) : "v"(s), "v"(r));
    return d;
}
template<int SIGN>
__device__ __forceinline__ cf2 rot90(cf2 z) {
    return (SIGN < 0) ? (cf2){z.y, -z.x} : (cf2){-z.y, z.x};
}
template<int SIGN>
__device__ __forceinline__ cf2 ldT(const cf2* __restrict__ T, int idx) {
    cf2 t = T[idx];
    if (SIGN > 0) t.y = -t.y;
    return t;
}

// LDS bank swizzle. Even XOR keeps float4 pair adjacency; involution.
__device__ __forceinline__ int swz(int i) { return i ^ (((i >> 5) & 15) << 1); }

// Digit reversal for fwd's radix 8,8,8,8,2 DIF ladder.
__device__ __forceinline__ int pos8(int f) {
    return ((f & 7) << 10) | (((f >> 3) & 7) << 7) |
           (((f >> 6) & 7) << 4) | (((f >> 9) & 7) << 1) | ((f >> 12) & 1);
}

// ---------------- radix-16 pieces (inv kernel) ----------------
template<int SIGN>
__device__ __forceinline__ void dft16(cf2 x[16]) {
    const float S = (SIGN < 0) ? -1.f : 1.f;
    const cf2 w1 = {0.9238795325112867f, S * 0.3826834323650898f};
    const cf2 w2 = {0.7071067811865476f, S * 0.7071067811865476f};
    const cf2 w3 = {0.3826834323650898f, S * 0.9238795325112867f};
    cf2 v[16];
    #pragma unroll
    for (int n1 = 0; n1 < 4; ++n1) {
        cf2 a0 = x[n1], a1 = x[n1+4], a2 = x[n1+8], a3 = x[n1+12];
        cf2 t0 = a0 + a2, t2 = a0 - a2;
        cf2 t1 = a1 + a3, t3 = rot90<SIGN>(a1 - a3);
        cf2 u0 = t0 + t1, u1 = t2 + t3;
        cf2 u2 = t0 - t1, u3 = t2 - t3;
        if (n1 == 1) { u1 = cmul(u1, w1); u2 = cmul(u2, w2); u3 = cmul(u3, w3); }
        else if (n1 == 2) { u1 = cmul(u1, w2); u2 = rot90<SIGN>(u2);
                            u3 = rot90<SIGN>(cmul(u3, w2)); }
        else if (n1 == 3) { u1 = cmul(u1, w3); u2 = rot90<SIGN>(cmul(u2, w2));
                            u3 = -cmul(u3, w1); }
        v[0*4+n1] = u0; v[1*4+n1] = u1; v[2*4+n1] = u2; v[3*4+n1] = u3;
    }
    #pragma unroll
    for (int r = 0; r < 4; ++r) {
        cf2 a0 = v[r*4+0], a1 = v[r*4+1], a2 = v[r*4+2], a3 = v[r*4+3];
        cf2 t0 = a0 + a2, t2 = a0 - a2;
        cf2 t1 = a1 + a3, t3 = rot90<SIGN>(a1 - a3);
        x[r]    = t0 + t1; x[r+4]  = t2 + t3;
        x[r+8]  = t0 - t1; x[r+12] = t2 - t3;
    }
}

template<int SIGN>
__device__ __forceinline__ void butterfly16(cf2* A, const int idx[16], cf2 w1) {
    cf2 x[16];
    #pragma unroll
    for (int n = 0; n < 16; ++n) x[n] = A[idx[n]];
    dft16<SIGN>(x);
    A[idx[0]] = x[0];
    A[idx[1]] = cmul(x[1], w1);
    const cf2 w2 = cmul(w1, w1);
    A[idx[2]] = cmul(x[2], w2);
    const cf2 w3 = cmul(w1, w2);
    A[idx[3]] = cmul(x[3], w3);
    const cf2 w4 = cmul(w2, w2);
    A[idx[4]] = cmul(x[4], w4);
    A[idx[5]] = cmul(x[5], cmul(w1, w4));
    A[idx[6]] = cmul(x[6], cmul(w2, w4));
    A[idx[7]] = cmul(x[7], cmul(w3, w4));
    const cf2 w8 = cmul(w4, w4);
    A[idx[8]]  = cmul(x[8],  w8);
    A[idx[9]]  = cmul(x[9],  cmul(w1, w8));
    A[idx[10]] = cmul(x[10], cmul(w2, w8));
    A[idx[11]] = cmul(x[11], cmul(w3, w8));
    const cf2 w12 = cmul(w4, w8);
    A[idx[12]] = cmul(x[12], w12);
    A[idx[13]] = cmul(x[13], cmul(w1, w12));
    A[idx[14]] = cmul(x[14], cmul(w2, w12));
    A[idx[15]] = cmul(x[15], cmul(w3, w12));
}

// ---------------- radix-8 pieces (fwd kernel) ----------------
template<int SIGN>
__device__ __forceinline__ void dft8(cf2 x[8]) {
    const float R2 = 0.70710678118654752f;
    const cf2 w81 = { R2, SIGN * R2 };
    const cf2 w83 = { -R2, SIGN * R2 };
    cf2 u0 = x[0] + x[4], u1 = x[1] + x[5], u2 = x[2] + x[6], u3 = x[3] + x[7];
    cf2 v0 = x[0] - x[4];
    cf2 v1 = cmul(x[1] - x[5], w81);
    cf2 v2 = rot90<SIGN>(x[2] - x[6]);
    cf2 v3 = cmul(x[3] - x[7], w83);
    cf2 t0 = u0 + u2, t2 = u0 - u2;
    cf2 t1 = u1 + u3, t3 = rot90<SIGN>(u1 - u3);
    x[0] = t0 + t1; x[2] = t2 + t3; x[4] = t0 - t1; x[6] = t2 - t3;
    cf2 s0 = v0 + v2, s2 = v0 - v2;
    cf2 s1 = v1 + v3, s3 = rot90<SIGN>(v1 - v3);
    x[1] = s0 + s1; x[3] = s2 + s3; x[5] = s0 - s1; x[7] = s2 - s3;
}

template<int SIGN>
__device__ __forceinline__ void butterfly8(cf2* A, const int idx[8], cf2 w1) {
    cf2 x[8];
    #pragma unroll
    for (int n = 0; n < 8; ++n) x[n] = A[idx[n]];
    dft8<SIGN>(x);
    A[idx[0]] = x[0];
    A[idx[1]] = cmul(x[1], w1);
    const cf2 w2 = cmul(w1, w1);
    A[idx[2]] = cmul(x[2], w2);
    const cf2 w3 = cmul(w1, w2);
    A[idx[3]] = cmul(x[3], w3);
    const cf2 w4 = cmul(w2, w2);
    A[idx[4]] = cmul(x[4], w4);
    A[idx[5]] = cmul(x[5], cmul(w1, w4));
    A[idx[6]] = cmul(x[6], cmul(w2, w4));
    A[idx[7]] = cmul(x[7], cmul(w3, w4));
}

// ---------------------------------------------------------------------------
// Kernel 1: forward real FFT (length 16384) via 8192-pt complex FFT.
// Radix 8,8,8,8,2 ladder, 1024 threads (R9). Blocks [NSIG, NSIG+16) build the
// twiddle table T via quadrant-reduced float sincos. W blocks (sig 64/65)
// write V(f) = conj(W(f)) * e^{-i pi k/8192}, k = 4094*f mod 16384.
// ---------------------------------------------------------------------------
__global__ __launch_bounds__(NTF, 4)
void fwd_fft_kernel(const float* __restrict__ xi, const float* __restrict__ w,
                    const float* __restrict__ tmpl, cf2* __restrict__ Tw,
                    cf2* __restrict__ spec) {
    __shared__ __attribute__((aligned(16))) cf2 A[M_LEN];   // 64 KB
    const int sig = blockIdx.x;
    const int tid = threadIdx.x;

    if (sig >= NSIG) {   // twiddle writer: T[k] = e^{-2 pi i k / 16384}
        const int k = (sig - NSIG) * NTF + tid;
        const int quad = k >> 12, mm = k & 4095;
        float s, c; __sincosf(PI_F * (float)mm / 8192.f, &s, &c);
        cf2 v;   // (cos th, -sin th), th = pi k/8192 = quad*pi/2 + t
        if      (quad == 0) v = (cf2){ c, -s};
        else if (quad == 1) v = (cf2){-s, -c};
        else if (quad == 2) v = (cf2){-c,  s};
        else                v = (cf2){ s,  c};
        Tw[k] = v;
        return;
    }

    const float* src;
    int nre;
    if (sig < 64)      { src = xi   + sig * L_LEN;         nre = L_LEN; }
    else if (sig < 66) { src = w    + (sig - 64) * L_LEN;  nre = L_LEN; }
    else               { src = tmpl + (sig - 66) * KT_LEN; nre = KT_LEN; }
    const bool isW = (sig >= 64 && sig < 66);
    const int nc = nre >> 1;
    const float4* s4 = (const float4*)src;
    const int g0 = tid ^ ((tid >> 4) & 15);
    #pragma unroll
    for (int m = 0; m < 4; ++m) {
        const int u = 2*tid + 2048*m;
        float4 vv = (u < nc) ? s4[tid + 1024*m] : make_float4(0.f, 0.f, 0.f, 0.f);
        ((float4*)A)[g0 + 1024*m] = vv;
    }
    __syncthreads();

    {   // stage 1: stride 1024, w1 = W_8192^tid
        int idx[8]; const int b0 = swz(tid);
        #pragma unroll
        for (int n = 0; n < 8; ++n) idx[n] = b0 + 1024*n;
        float sn, cs; __sincosf(-PI_F * (float)(2*tid) / 8192.f, &sn, &cs);
        butterfly8<-1>(A, idx, (cf2){cs, sn});
    }
    __syncthreads();
    {   // stage 2: stride 128, w1 = W_1024^j
        const int blk = tid >> 7, j = tid & 127, jb = blk*1024;
        const int jsw = j ^ (((j >> 5) & 3) << 1);
        int idx[8];
        #pragma unroll
        for (int n = 0; n < 8; ++n) idx[n] = jb + 128*n + (jsw ^ ((n & 3) << 3));
        float sn, cs; __sincosf(-PI_F * (float)(16*j) / 8192.f, &sn, &cs);
        butterfly8<-1>(A, idx, (cf2){cs, sn});
    }
    __syncthreads();
    {   // stage 3: stride 16, w1 = W_128^j
        const int blk = tid >> 4, j = tid & 15;
        const int base = blk*128 + j, bx = (blk & 3) << 3;
        int idx[8];
        #pragma unroll
        for (int n = 0; n < 8; ++n) idx[n] = (base + 16*n) ^ bx ^ ((n >> 1) << 1);
        float sn, cs; __sincosf(-PI_F * (float)(128*j) / 8192.f, &sn, &cs);
        butterfly8<-1>(A, idx, (cf2){cs, sn});
    }
    __syncthreads();
    {   // stage 4: stride 2, w1 = W_16^j (constant)
        const int blk = tid >> 1, j = tid & 1;
        const int Xa = ((blk >> 1) & 15) << 1;
        const int base = ((blk << 4) | j) ^ (Xa & 16);
        const int xv = Xa & 14;
        int idx[8];
        #pragma unroll
        for (int n = 0; n < 8; ++n) idx[n] = base + ((2*n) ^ xv);
        cf2 w1 = j ? (cf2){C8, -S8} : (cf2){1.f, 0.f};
        butterfly8<-1>(A, idx, w1);
    }
    __syncthreads();
    // Final radix-2 (stride 1, no twiddle), b128 in-place.
    #pragma unroll
    for (int m = 0; m < 4; ++m) {
        float4 pq = ((float4*)A)[g0 + 1024*m];
        ((float4*)A)[g0 + 1024*m] = make_float4(pq.x + pq.z, pq.y + pq.w,
                                                pq.x - pq.z, pq.y - pq.w);
    }
    __syncthreads();

    // Untangle packed result to real-signal spectrum X[f], f = 0..M.
    cf2* out = spec + (size_t)sig * SPEC_STRIDE;
    #pragma unroll
    for (int m = 0; m < 8; ++m) {
        const int f = tid + 1024*m;
        const int fb = (M_LEN - f) & (M_LEN - 1);
        cf2 Za = A[swz(pos8(f))];
        cf2 Zb = A[swz(pos8(fb))];
        cf2 E = (cf2){0.5f*(Za.x + Zb.x), 0.5f*(Za.y - Zb.y)};
        cf2 D = (cf2){Za.x - Zb.x, Za.y + Zb.y};
        cf2 O = (cf2){0.5f*D.y, -0.5f*D.x};
        float sn, cs;
        __sincosf(-PI_F * (float)f / 8192.f, &sn, &cs);
        cf2 val = E + (cf2){cs*O.x - sn*O.y, cs*O.y + sn*O.x};
        if (isW) {   // V(f) = conj(W(f)) * e^{-i pi k/8192}, k exact int mod
            const int k = (4094 * f) & (L_LEN - 1);
            float psn, pcs; __sincosf(-PI_F * (float)k / 8192.f, &psn, &pcs);
            val = cmul((cf2){val.x, -val.y}, (cf2){pcs, psn});
        }
        out[f] = val;
    }
    if (tid == 0) {   // f = 8192
        cf2 Za = A[swz(0)];
        cf2 val = (cf2){Za.x - Za.y, 0.f};
        if (isW) {   // k(8192) = 8192 -> phase = (-1, 0)
            val = (cf2){-val.x, 0.f};
        }
        out[M_LEN] = val;
    }
}

// ---------------------------------------------------------------------------
// Kernel 2: per (b,n,c): S[f] = X[f]*V[f]*conj(H[f]); Hermitian pack fused
// into the product pass (fully VOP3P-packed, R11; 2x scale folded into the
// final divide); 3 radix-16 LDS stages; final radix-2 fused with max.
// ---------------------------------------------------------------------------
__global__ __launch_bounds__(NTI, 4)
void inv_fft_kernel(const cf2* __restrict__ spec, const cf2* __restrict__ T,
                    const float* __restrict__ hh, float* __restrict__ zarr) {
    __shared__ __attribute__((aligned(16))) cf2 A[M_LEN];   // 64 KB
    const int idx0 = blockIdx.x;
    const int c = idx0 & 1;
    const int n = (idx0 >> 1) % NTPL;
    const int b = idx0 / (2 * NTPL);
    const int tid = threadIdx.x;

    const cf2* Xs = spec + (size_t)(b*2 + c)      * SPEC_STRIDE;
    const cf2* Vs = spec + (size_t)(64 + c)       * SPEC_STRIDE;
    const cf2* Hs = spec + (size_t)(66 + n*2 + c) * SPEC_STRIDE;
    const float4* X4 = (const float4*)Xs;
    const float4* V4 = (const float4*)Vs;
    const float4* H4 = (const float4*)Hs;
    const float4* T4 = (const float4*)T;
    const int g0 = tid ^ ((tid >> 4) & 15);

    // Fused product + Hermitian pack, all VOP3P. Thread t handles f =
    // 2t+1024m+{0,1} (f in [0,4096)) and partners 8192-f. Writes all of
    // Z'[0..8191] with a uniform 2x scale (0.5 dropped; f=4096 doubled;
    // final zarr divide uses 2*M_LEN).
    #pragma unroll
    for (int m = 0; m < 4; ++m) {
        const int u = 2*tid + 1024*m;
        float4 xf = X4[tid + 512*m], vf = V4[tid + 512*m], hf = H4[tid + 512*m];
        cf2 P0 = cmulc(cmul((cf2){xf.x, xf.y}, (cf2){vf.x, vf.y}), (cf2){hf.x, hf.y});
        cf2 P1 = cmulc(cmul((cf2){xf.z, xf.w}, (cf2){vf.z, vf.w}), (cf2){hf.z, hf.w});
        cf2 Q0 = cmulc(cmul(Xs[M_LEN - u],     Vs[M_LEN - u]),     Hs[M_LEN - u]);
        cf2 Q1 = cmulc(cmul(Xs[M_LEN - 1 - u], Vs[M_LEN - 1 - u]), Hs[M_LEN - 1 - u]);
        float4 tw = T4[tid + 512*m];          // T[u], T[u+1]
        cf2 t0 = (cf2){tw.x, tw.y}, t1 = (cf2){tw.z, tw.w};
        cf2 Sp0 = pk_addch(P0, Q0), Sm0 = pk_subcl(P0, Q0);
        cf2 R0 = cmulca(t0, Sm0);
        cf2 Sp1 = pk_addch(P1, Q1), Sm1 = pk_subcl(P1, Q1);
        cf2 R1 = cmulca(t1, Sm1);
        cf2 Z0 = pk_compose1(Sp0, R0);        // Z'[u]     = Sp + i*R
        cf2 Z1 = pk_compose1(Sp1, R1);
        ((float4*)A)[g0 + 512*m] = make_float4(Z0.x, Z0.y, Z1.x, Z1.y);
        if (u > 0) A[swz(M_LEN - u)] = pk_compose2(Sp0, R0);  // conj(Sp - i*R)
        A[swz(M_LEN - 1 - u)] = pk_compose2(Sp1, R1);
    }
    if (tid == 0) {   // f = 4096 (self-paired), doubled to match the 2x scale
        cf2 S = cmulc(cmul(Xs[4096], Vs[4096]), Hs[4096]);
        A[swz(4096)] = (cf2){2.f * S.x, -2.f * S.y};
    }
    __syncthreads();

    {   // stage 1: stride 512, es = 2*tid
        int idx[16]; const int b0 = swz(tid);
        #pragma unroll
        for (int nn = 0; nn < 16; ++nn) idx[nn] = b0 + 512*nn;
        butterfly16<+1>(A, idx, ldT<+1>(T, 2*tid));
    }
    __syncthreads();
    {   // stage 2: stride 32, es = 32*j
        const int blk = tid >> 5, j = tid & 31, jb = blk*512;
        int idx[16];
        #pragma unroll
        for (int nn = 0; nn < 16; ++nn) idx[nn] = jb + 32*nn + (j ^ (2*nn));
        butterfly16<+1>(A, idx, ldT<+1>(T, 32*j));
    }
    __syncthreads();
    {   // stage 3: stride 2, es = 512*j
        const int blk = tid >> 1, j = tid & 1;
        const int xv = (blk & 15) << 1, b3 = blk*32 + j;
        int idx[16];
        #pragma unroll
        for (int nn = 0; nn < 16; ++nn) idx[nn] = b3 + ((2*nn) ^ xv);
        cf2 w1 = j ? (cf2){C16, S16} : (cf2){1.f, 0.f};
        butterfly16<+1>(A, idx, w1);
    }
    __syncthreads();

    // Final radix-2 fused with max over re/im of every time sample (b128).
    float mx = -INFINITY;
    #pragma unroll
    for (int m = 0; m < 8; ++m) {
        float4 pq = ((const float4*)A)[g0 + 512*m];
        mx = fmaxf(mx, fmaxf(fmaxf(pq.x + pq.z, pq.y + pq.w),
                             fmaxf(pq.x - pq.z, pq.y - pq.w)));
    }
    __syncthreads();   // all reads of A done before reusing it as scratch
    for (int off = 32; off > 0; off >>= 1)
        mx = fmaxf(mx, __shfl_xor(mx, off));
    const int lane = tid & 63, wv = tid >> 6;   // 8 waves
    float* redf = (float*)A;
    if (lane == 0) redf[wv] = mx;
    __syncthreads();
    if (tid == 0) {
        float mm = redf[0];
        for (int i = 1; i < NTI/64; ++i) mm = fmaxf(mm, redf[i]);
        zarr[(b*2 + c)*NTPL + n] = mm / (2.f * (float)M_LEN * hh[n*2 + c]);
    }
}

// ---------------------------------------------------------------------------
// Kernel 3: tiny CNN/MLP head. One block per batch element.
// R12: all weights staged in LDS (coalesced), all MAC loops unrolled over
// LDS reads, fc1 parallelized 32 outputs x 8 lanes + shfl_xor tree.
// W3 stored with row stride 132 -> fc1 read pattern is <=2-way on banks.
// ---------------------------------------------------------------------------
#define W1_OFF 0        // 16x6 = 96
#define B1_OFF 96       // 16
#define W2_OFF 112      // 32x48 = 1536
#define B2_OFF 1648     // 32
#define W3_OFF 1680     // 32x132 (padded from 128) = 4224
#define B3_OFF 5904     // 32
#define W4_OFF 5936     // 2x32 = 64
#define B4_OFF 6000     // 2
#define WSM_SZ 6002

__global__ __launch_bounds__(256)
void head_kernel(const float* __restrict__ zarr,
                 const float* __restrict__ W1, const float* __restrict__ b1,
                 const float* __restrict__ W2, const float* __restrict__ b2,
                 const float* __restrict__ W3, const float* __restrict__ b3,
                 const float* __restrict__ W4, const float* __restrict__ b4,
                 float* __restrict__ out) {
    __shared__ float wsm[WSM_SZ];
    __shared__ float zl[2*NTPL];
    __shared__ float s1[16*48];
    __shared__ float p1[16*16];
    __shared__ float s2[32*14];
    __shared__ float hflat[128];
    __shared__ float h1[32];
    const int b = blockIdx.x, tid = threadIdx.x;

    // Cooperative weight staging (coalesced global reads).
    for (int i = tid; i < 96;   i += 256) wsm[W1_OFF + i] = W1[i];
    if (tid < 16)                         wsm[B1_OFF + tid] = b1[tid];
    for (int i = tid; i < 1536; i += 256) wsm[W2_OFF + i] = W2[i];
    if (tid < 32)                         wsm[B2_OFF + tid] = b2[tid];
    for (int i = tid; i < 4096; i += 256)
        wsm[W3_OFF + (i >> 7)*132 + (i & 127)] = W3[i];
    if (tid < 32)                         wsm[B3_OFF + tid] = b3[tid];
    if (tid < 64)                         wsm[W4_OFF + tid] = W4[tid];
    if (tid < 2)                          wsm[B4_OFF + tid] = b4[tid];
    for (int i = tid; i < 2*NTPL; i += 256) zl[i] = zarr[b*2*NTPL + i];
    __syncthreads();

    // conv1 + sigmoid: 16 ch x 48 t
    for (int i = tid; i < 16*48; i += 256) {
        const int o = i / 48, t = i % 48;
        float acc = wsm[B1_OFF + o];
        #pragma unroll
        for (int cc = 0; cc < 2; ++cc)
            #pragma unroll
            for (int k = 0; k < 3; ++k)
                acc += zl[cc*NTPL + t + k] * wsm[W1_OFF + o*6 + cc*3 + k];
        s1[i] = 1.f / (1.f + __expf(-acc));
    }
    __syncthreads();
    // pool1: 16 x 16
    for (int i = tid; i < 16*16; i += 256) {
        const int o = i / 16, u = i % 16;
        p1[i] = fmaxf(fmaxf(s1[o*48 + 3*u], s1[o*48 + 3*u+1]), s1[o*48 + 3*u+2]);
    }
    __syncthreads();
    // conv2 + sigmoid: 32 ch x 14 t (fully unrolled, LDS reads only)
    for (int i = tid; i < 32*14; i += 256) {
        const int o = i / 14, t = i % 14;
        float acc = wsm[B2_OFF + o];
        #pragma unroll
        for (int cc = 0; cc < 16; ++cc)
            #pragma unroll
            for (int k = 0; k < 3; ++k)
                acc += p1[cc*16 + t + k] * wsm[W2_OFF + o*48 + cc*3 + k];
        s2[o*14 + t] = 1.f / (1.f + __expf(-acc));
    }
    __syncthreads();
    // pool2 -> hflat[128]
    for (int i = tid; i < 128; i += 256) {
        const int o = i / 4, u = i % 4;
        hflat[i] = fmaxf(fmaxf(s2[o*14 + 3*u], s2[o*14 + 3*u+1]), s2[o*14 + 3*u+2]);
    }
    __syncthreads();
    // fc1 + relu: 32 outputs x 8 lanes each, shfl_xor tree reduce.
    {
        const int o = tid >> 3, lg = tid & 7;
        float acc = 0.f;
        #pragma unroll
        for (int k = 0; k < 16; ++k)
            acc += hflat[lg + 8*k] * wsm[W3_OFF + o*132 + lg + 8*k];
        acc += __shfl_xor(acc, 1);
        acc += __shfl_xor(acc, 2);
        acc += __shfl_xor(acc, 4);
        if (lg == 0) h1[o] = fmaxf(acc + wsm[B3_OFF + o], 0.f);
    }
    __syncthreads();
    // fc2: 2 outputs x 32 lanes, shfl_xor tree (masks <32 keep halves apart).
    if (tid < 64) {
        const int o = tid >> 5, j = tid & 31;
        float p = h1[j] * wsm[W4_OFF + o*32 + j];
        p += __shfl_xor(p, 1);
        p += __shfl_xor(p, 2);
        p += __shfl_xor(p, 4);
        p += __shfl_xor(p, 8);
        p += __shfl_xor(p, 16);
        if (j == 0) out[b*2 + o] = p + wsm[B4_OFF + o];
    }
}

extern "C" void kernel_launch(void* const* d_in, const int* in_sizes, int n_in,
                              void* d_out, int out_size, void* d_ws, size_t ws_size,
                              hipStream_t stream) {
    const float* xi   = (const float*)d_in[0];
    const float* Sw   = (const float*)d_in[1];
    const float* tmpl = (const float*)d_in[2];
    const float* hh   = (const float*)d_in[3];
    const float* W1   = (const float*)d_in[4];
    const float* b1   = (const float*)d_in[5];
    const float* W2   = (const float*)d_in[6];
    const float* b2   = (const float*)d_in[7];
    const float* W3   = (const float*)d_in[8];
    const float* b3   = (const float*)d_in[9];
    const float* W4   = (const float*)d_in[10];
    const float* b4   = (const float*)d_in[11];
    float* out = (float*)d_out;

    cf2* T16  = (cf2*)d_ws;                         // 16384 cf2 = 128 KB
    cf2* spec = T16 + 16384;                        // NSIG * SPEC_STRIDE cf2
    float* zarr = (float*)(spec + (size_t)NSIG * SPEC_STRIDE);

    // fwd grid: NSIG FFT blocks + 16 twiddle-table writer blocks (NTF=1024).
    // W blocks write V = conj(W)*phase, so no premul kernel is needed.
    fwd_fft_kernel<<<dim3(NSIG + 16), dim3(NTF), 0, stream>>>(xi, Sw, tmpl, T16, spec);
    inv_fft_kernel<<<dim3(BB * NTPL * 2), dim3(NTI), 0, stream>>>(spec, T16, hh, zarr);
    head_kernel<<<dim3(BB), dim3(256), 0, stream>>>(zarr, W1, b1, W2, b2, W3, b3, W4, b4, out);
}